// Round 8
// baseline (267.531 us; speedup 1.0000x reference)
//
#include <hip/hip_runtime.h>
#include <hip/hip_bf16.h>

// Problem constants (from reference)
#define Hh    100
#define NN    1024     // B*L
#define BB    64
#define LL    16
#define EE    2048
#define NNODE 40000

#define BSPL  8        // b-loop split (slices)
#define BPB   (BB / BSPL)      // 8 b's per slice
#define PFR   8        // fragments per panel: f = t*4+ks, t in 0..1, ks in 0..3
#define PPAN  (PFR * 64 * 8)   // u16 per panel (4096)
#define GJ    4        // j-groups per wave (wave covers 64 embed rows)
#define EBS   104      // padded bf16 embed row stride (u16)
#define GRB   2        // rows per k_gruatt block

typedef unsigned short u16;
typedef __attribute__((ext_vector_type(8))) short short8;   // 8 bf16 = 4 VGPRs
typedef __attribute__((ext_vector_type(4))) float f32x4;    // MFMA C/D

__device__ __forceinline__ float bf2f(u16 u) {
    union { unsigned int i; float f; } v;
    v.i = ((unsigned int)u) << 16;
    return v.f;
}

__device__ __forceinline__ u16 f2bf(float f) {
    unsigned int x = __float_as_uint(f);
    unsigned int lsb = (x >> 16) & 1u;
    x += 0x7fffu + lsb;              // round-to-nearest-even
    return (u16)(x >> 16);
}

__device__ __forceinline__ float sigmoidf_(float x) {
    return 1.0f / (1.0f + expf(-x));
}

template <bool BF>
__device__ __forceinline__ float ldv(const void* p, size_t i) {
    if (BF) return bf2f(((const u16*)p)[i]);
    return ((const float*)p)[i];
}
__device__ __forceinline__ float ldvf(int flag, const void* p, size_t i) {
    return flag ? ldv<true>(p, i) : ldv<false>(p, i);
}

// ---------------------------------------------------------------------------
// k_cvt (+ gated ecvt): per-BLOCK dtype self-detect (256 embed samples —
// fp32 misdetection prob ~2^-128). Blocks 0..481: convert/transpose small
// tensors to fp32 + zero agg0. Blocks 482..: embed -> padded bf16 EB, but
// ONLY when input is fp32 (bf16 input: raw embed is read directly by
// k_score — the EB copy is redundant; ks=3 tail cols are killed by zero A).
template <bool BF>
__device__ void cvt_impl(int t,
                         const void* ew, const void* ggc, const void* wih, const void* whh,
                         const void* bih, const void* bhh, const void* W1w, const void* W1b,
                         const void* W2w, const void* W2b, const void* Wtw, const void* Wtb,
                         const void* qw, const void* qb, const void* W3w, const void* W3b,
                         float* __restrict__ W) {
    const void* src; int si; int doff; int di;
    if      (t <   2048) { src = ew;  si = t;          doff = 0;      di = si; }
    else if (t <  12048) { src = ggc; si = t - 2048;   doff = 2048;   di = si; }                      // row-major
    else if (t <  42048) { src = wih; si = t - 12048;  doff = 12048;  { int r = si / 100, k = si - r * 100; di = k * 800 + (r % 100) * 8 + r / 100; } }
    else if (t <  72048) { src = whh; si = t - 42048;  doff = 12048;  { int r = si / 100, k = si - r * 100; di = k * 800 + (r % 100) * 8 + 3 + r / 100; } }
    else if (t <  72348) { src = bih; si = t - 72048;  doff = 92048;  di = si; }
    else if (t <  72648) { src = bhh; si = t - 72348;  doff = 92352;  di = si; }
    else if (t <  82648) { src = W1w; si = t - 72648;  doff = 92656;  di = (si % 100) * 100 + si / 100; }   // T
    else if (t <  82748) { src = W1b; si = t - 82648;  doff = 102656; di = si; }
    else if (t <  92748) { src = W2w; si = t - 82748;  doff = 102768; di = (si % 100) * 100 + si / 100; }   // T
    else if (t <  92848) { src = W2b; si = t - 92748;  doff = 112768; di = si; }
    else if (t < 102848) { src = Wtw; si = t - 92848;  doff = 112880; di = (si % 100) * 100 + si / 100; }   // T
    else if (t < 102948) { src = Wtb; si = t - 102848; doff = 122880; di = si; }
    else if (t < 103048) { src = qw;  si = t - 102948; doff = 122992; di = si; }
    else if (t < 103049) { src = qb;  si = t - 103048; doff = 123104; di = si; }
    else if (t < 123049) { src = W3w; si = t - 103049; doff = 123120; di = (si % 200) * 100 + si / 200; }   // T
    else                 { src = W3b; si = t - 123049; doff = 143120; di = si; }
    W[doff + di] = ldv<BF>(src, si);
}

__global__ void __launch_bounds__(256) k_cvt(const void* embed_raw, int* __restrict__ flag,
                      const void* ew, const void* ggc, const void* wih, const void* whh,
                      const void* bih, const void* bhh, const void* W1w, const void* W1b,
                      const void* W2w, const void* W2b, const void* Wtw, const void* Wtb,
                      const void* qw, const void* qb, const void* W3w, const void* W3b,
                      float* __restrict__ W, float* __restrict__ agg0,
                      u16* __restrict__ EB) {
    __shared__ int cnt;
    if (threadIdx.x == 0) cnt = 0;
    __syncthreads();
    const u16* eb16 = (const u16*)embed_raw;
    {
        float v = bf2f(eb16[threadIdx.x]);
        if (!(fabsf(v) <= 0.5f)) atomicAdd(&cnt, 1);   // counts NaN too
    }
    __syncthreads();
    const bool bf = (cnt == 0);
    const int bid = blockIdx.x;
    if (bid == 0 && threadIdx.x == 0) flag[0] = bf ? 1 : 0;
    if (bid < 482) {
        int t = bid * 256 + threadIdx.x;
        if (t < NN * Hh) agg0[t] = 0.0f;             // zero scatter target
        if (t >= 123149) return;
        if (bf) cvt_impl<true >(t, ew, ggc, wih, whh, bih, bhh, W1w, W1b, W2w, W2b, Wtw, Wtb, qw, qb, W3w, W3b, W);
        else    cvt_impl<false>(t, ew, ggc, wih, whh, bih, bhh, W1w, W1b, W2w, W2b, Wtw, Wtb, qw, qb, W3w, W3b, W);
    } else {
        if (bf) return;                              // bf16: EB not needed
        // ecvt (fp32 input only): embed -> padded bf16 + zeroed guard row
        int t = (bid - 482) * 256 + threadIdx.x;
        const int total = (NNODE + 1) * (EBS / 2);
        if (t >= total) return;
        int r = t / (EBS / 2), c2 = t - r * (EBS / 2);
        int k0 = c2 * 2;
        unsigned int w = 0;
        if (r < NNODE && k0 + 1 < Hh) {
            float2 e2 = *(const float2*)&((const float*)embed_raw)[(size_t)r * Hh + k0];
            w = (unsigned int)f2bf(e2.x) | ((unsigned int)f2bf(e2.y) << 16);
        }
        ((unsigned int*)EB)[t] = w;
    }
}

// ---------------------------------------------------------------------------
// k_scatter2: agg0[dst] += ew[e] * h0[src]  (h0 = embed[x[src]], gathered
// directly — the GGC GEMM is applied AFTER aggregation in k_gruatt, valid by
// linearity). 2 cols per thread (u32/float2 loads).
__global__ void k_scatter2(const int* __restrict__ flag, const int* __restrict__ ei,
                           const float* __restrict__ ew, const int* __restrict__ x,
                           const void* __restrict__ embed, float* __restrict__ agg0) {
    int t = blockIdx.x * 256 + threadIdx.x;
    if (t >= EE * (Hh / 2)) return;
    int e = t / (Hh / 2), j2 = t - e * (Hh / 2);
    int j = j2 * 2;
    int src = ei[e], dst = ei[EE + e];
    const int fl = flag[0];
    float w = ew[e];
    float h0, h1v;
    size_t base = (size_t)x[src] * Hh + j;
    if (fl) {
        unsigned int u = *(const unsigned int*)&((const u16*)embed)[base];
        h0 = bf2f((u16)(u & 0xffff));
        h1v = bf2f((u16)(u >> 16));
    } else {
        float2 f2 = *(const float2*)&((const float*)embed)[base];
        h0 = f2.x; h1v = f2.y;
    }
    atomicAdd(&agg0[dst * Hh + j], w * h0);
    atomicAdd(&agg0[dst * Hh + j + 1], w * h1v);
}

// ---------------------------------------------------------------------------
// k_gruatt v2: 512 threads/block, k-loops split 2-way (kh = tid>>8), partials
// combined in LDS. (Round-5 measured fix for latency-bound regime.)
__global__ void __launch_bounds__(512) k_gruatt(const int* __restrict__ flag,
                      const int* __restrict__ x, const void* __restrict__ embed,
                      const float* __restrict__ agg0, const float* __restrict__ ggc_f,
                      const float* __restrict__ wC,
                      const float* __restrict__ bih, const float* __restrict__ bhh,
                      const float* __restrict__ W1T, const float* __restrict__ W1b,
                      const float* __restrict__ W2T, const float* __restrict__ W2b,
                      const float* __restrict__ WtT, const float* __restrict__ Wtb,
                      float* __restrict__ h1, float* __restrict__ Q2g,
                      float* __restrict__ Q1g, u16* __restrict__ P) {
    __shared__ float sG[GRB * Hh];    // agg0 rows
    __shared__ float sH0[GRB * Hh];   // embed rows
    __shared__ float sA[GRB * Hh];    // agg rows (post-GGC)
    __shared__ float sV[GRB * Hh];    // h1 rows
    __shared__ float sVT[GRB * Hh];   // VTs rows
    __shared__ float sPx[6 * 512];    // k-split partials (stride-1 per slot)
    const int tid = threadIdx.x;
    const int r0 = blockIdx.x * GRB;
    const int fl = flag[0];
    const int kh = tid >> 8;              // k-half
    const int o  = tid & 255;             // work item (i,j)
    const bool valid = (o < GRB * Hh);
    const int i = o / Hh, j = o - i * Hh; // meaningful when valid
    const int k0 = kh * 50, k1 = k0 + 50;

    // Load agg0 + gathered embed rows (contiguous per row; coalesced).
    if (tid < GRB * Hh) {
        sG[tid] = agg0[r0 * Hh + tid];
    } else if (tid < 2 * GRB * Hh) {
        int o2 = tid - GRB * Hh;
        int i2 = o2 / Hh, j2 = o2 - i2 * Hh;
        sH0[o2] = ldvf(fl, embed, (size_t)x[r0 + i2] * Hh + j2);
    }
    __syncthreads();

    // Phase 1: agg = agg0 @ ggc (k-split partial)
    {
        float acc = 0.0f;
        if (valid) {
            const float* gi = sG + i * Hh;
#pragma unroll 5
            for (int k = k0; k < k1; ++k) acc += gi[k] * ggc_f[k * Hh + j];
        }
        sPx[tid] = acc;
    }
    __syncthreads();
    if (valid && kh == 0) sA[o] = sPx[tid] + sPx[tid + 256];
    __syncthreads();

    // Phase 2: GRU gate sums (6 accumulators, k-split)
    {
        float p0 = 0, p1 = 0, p2 = 0, p3 = 0, p4 = 0, p5 = 0;
        if (valid) {
            const float* ai = sA + i * Hh;
            const float* hi = sH0 + i * Hh;
            const float* wbase = wC + j * 8;
#pragma unroll 5
            for (int k = k0; k < k1; ++k) {
                float a = ai[k], h = hi[k];
                const float* wr = wbase + k * 800;
                float4 w0 = *(const float4*)wr;
                float2 w1 = *(const float2*)(wr + 4);
                p0 += a * w0.x;
                p1 += a * w0.y;
                p2 += a * w0.z;
                p3 += h * w0.w;
                p4 += h * w1.x;
                p5 += h * w1.y;
            }
        }
        sPx[tid] = p0;             sPx[512 + tid] = p1;
        sPx[1024 + tid] = p2;      sPx[1536 + tid] = p3;
        sPx[2048 + tid] = p4;      sPx[2560 + tid] = p5;
    }
    __syncthreads();
    if (valid && kh == 0) {
        float s_ir = bih[j] + sPx[tid] + sPx[tid + 256];
        float s_iz = bih[j + Hh] + sPx[512 + tid] + sPx[512 + tid + 256];
        float s_in = bih[j + 2 * Hh] + sPx[1024 + tid] + sPx[1024 + tid + 256];
        float s_hr = bhh[j] + sPx[1536 + tid] + sPx[1536 + tid + 256];
        float s_hz = bhh[j + Hh] + sPx[2048 + tid] + sPx[2048 + tid + 256];
        float s_hn = bhh[j + 2 * Hh] + sPx[2560 + tid] + sPx[2560 + tid + 256];
        float r = sigmoidf_(s_ir + s_hr);
        float z = sigmoidf_(s_iz + s_hz);
        float n = tanhf(s_in + r * s_hn);
        float hv = (1.0f - z) * n + z * sH0[o];
        sV[o] = hv;
        h1[r0 * Hh + o] = hv;
    }
    __syncthreads();

    // Phase 3: Q2 = h1@W2T+b, VTs = h1@WtT+b (k-split)
    {
        float a2 = 0.0f, at = 0.0f;
        if (valid) {
            const float* vi = sV + i * Hh;
#pragma unroll 5
            for (int k = k0; k < k1; ++k) {
                float vk = vi[k];
                a2 += vk * W2T[k * Hh + j];
                at += vk * WtT[k * Hh + j];
            }
        }
        sPx[tid] = a2;
        sPx[512 + tid] = at;
    }
    __syncthreads();
    if (valid && kh == 0) {
        Q2g[r0 * Hh + o] = sPx[tid] + sPx[tid + 256] + W2b[j];
        sVT[o] = sPx[512 + tid] + sPx[512 + tid + 256] + Wtb[j];
    }
    __syncthreads();

    // Q1 for session-final row (global row r0+1 == 16b+15)
    if ((r0 & 15) == 14 && tid < Hh) {
        const float* vl = sV + Hh;
        float a1 = 0.0f;
#pragma unroll 4
        for (int k = 0; k < Hh; ++k) a1 += vl[k] * W1T[k * Hh + tid];
        Q1g[(r0 >> 4) * Hh + tid] = a1 + W1b[tid];
    }
    // P fragment writes for our GRB rows, both t-tiles (t0=VTs, t1=V).
    const int b = r0 >> 4;
    if (tid < GRB * 2 * 4 * 4) {
        int ii = tid >> 5, rest = tid & 31;
        int tt = rest >> 4, ks = (rest >> 2) & 3, qq = rest & 3;
        int mm = (r0 & 15) + ii;
        int col0 = ks * 32 + qq * 8;
        const float* srow = (tt == 0 ? sVT : sV) + ii * Hh;
        short8 t8;
#pragma unroll
        for (int e = 0; e < 8; ++e) {
            int col = col0 + e;
            t8[e] = (short)f2bf(col < Hh ? srow[col] : 0.0f);
        }
        *(short8*)&P[((size_t)b * PFR + tt * 4 + ks) * 512 + (qq * 16 + mm) * 8] = t8;
    }
}

// ---------------------------------------------------------------------------
// k_score v12: att2 fused as a per-slice prologue (alpha/s_g/s_h for the
// slice's 8 b's computed in LDS — ~0.24 GFLOP chip-wide redundancy, deletes
// a kernel + launch gap + SD round-trip). Embed fragments: raw bf16 loads
// when input is bf16 (flag, uniform branch — EB conversion unnecessary since
// A is zero for k>=100); EB when fp32. BSPL=8, GJ=4, LDS panel double-buffer
// with register prefetch, max-free softmax.
__device__ __forceinline__ short8 load_efrag(const void* embed, bool bf, int j, int k0) {
    short8 v = {0, 0, 0, 0, 0, 0, 0, 0};
    if (j >= NNODE || k0 >= Hh) return v;
    if (bf) {
        const u16* row = (const u16*)embed + (size_t)j * Hh + k0;
        if (k0 + 8 <= Hh) {
            ushort4 a = *(const ushort4*)(row);
            ushort4 b = *(const ushort4*)(row + 4);
            v[0] = (short)a.x; v[1] = (short)a.y; v[2] = (short)a.z; v[3] = (short)a.w;
            v[4] = (short)b.x; v[5] = (short)b.y; v[6] = (short)b.z; v[7] = (short)b.w;
        } else {
            for (int e = 0; e < Hh - k0; ++e) v[e] = (short)row[e];
        }
    } else {
        const float* row = (const float*)embed + (size_t)j * Hh + k0;
        if (k0 + 8 <= Hh) {
            float4 a = *(const float4*)(row);
            float4 b = *(const float4*)(row + 4);
            v[0] = (short)f2bf(a.x); v[1] = (short)f2bf(a.y); v[2] = (short)f2bf(a.z); v[3] = (short)f2bf(a.w);
            v[4] = (short)f2bf(b.x); v[5] = (short)f2bf(b.y); v[6] = (short)f2bf(b.z); v[7] = (short)f2bf(b.w);
        } else {
            for (int e = 0; e < Hh - k0; ++e) v[e] = (short)f2bf(row[e]);
        }
    }
    return v;
}

#define JBLK  157   // ceil(40000/256)

template <int EMODE>
__global__ void __launch_bounds__(256) k_score(const int* __restrict__ flag,
                                               const void* __restrict__ embed,
                                               const u16* __restrict__ EB,
                                               const u16* __restrict__ P,
                                               const float* __restrict__ h1,
                                               const float* __restrict__ Q1g,
                                               const float* __restrict__ Q2g,
                                               const float* __restrict__ qw,
                                               const float* __restrict__ qb,
                                               const float* __restrict__ W3T,
                                               const float* __restrict__ W3b,
                                               void* __restrict__ out) {
    __shared__ alignas(16) u16 sPan[2][PPAN];    // 2 x 8192 B
    __shared__ float sAL[BPB][LL];               // alphas
    __shared__ float sSG[BPB * Hh];              // s_g
    __shared__ float sSH[BPB * Hh];              // s_h
    const int jb = blockIdx.x * 256;
    const int slice = blockIdx.y;
    const int b0 = slice * BPB;
    const int tid = threadIdx.x;
    const bool bf = (flag[0] != 0);
    const int wave = tid >> 6, lane = tid & 63;
    const int m = lane & 15, quad = lane >> 4;

    // B fragments first (global loads issue early; latency hides under the
    // attention prologue below).
    short8 Bf[GJ][4];
#pragma unroll
    for (int g = 0; g < GJ; ++g)
#pragma unroll
        for (int ks = 0; ks < 4; ++ks) {
            int j = jb + wave * 64 + g * 16 + m;
            if (bf) {
                Bf[g][ks] = load_efrag(embed, true, j, ks * 32 + quad * 8);
            } else if (EMODE) {
                short8 v = {0, 0, 0, 0, 0, 0, 0, 0};
                if (j < NNODE)
                    v = *(const short8*)&EB[(size_t)j * EBS + ks * 32 + quad * 8];
                Bf[g][ks] = v;
            } else {
                Bf[g][ks] = load_efrag(embed, false, j, ks * 32 + quad * 8);
            }
        }

    // --- Fused attention tail (was k_att2), for this slice's 8 b's ---
    // P0: alpha[bb][l], 128 pairs x 2 threads (j-halves), shfl combine.
    {
        int p = tid >> 1, hf = tid & 1;
        int bb = p >> 4, l = p & 15;
        const float* q1 = Q1g + (size_t)(b0 + bb) * Hh;
        const float* q2 = Q2g + ((size_t)(b0 + bb) * LL + l) * Hh;
        float acc = 0.0f;
        int js = hf * 50;
        for (int j = js; j < js + 50; ++j)
            acc += sigmoidf_(q1[j] + q2[j]) * qw[j];
        acc += __shfl_xor(acc, 1);
        if (hf == 0) sAL[bb][l] = acc + qb[0];
    }
    __syncthreads();
    // P1: s_g[bb][k] = sum_l alpha[bb][l] * V[bb,l][k]
    for (int it = tid; it < BPB * Hh; it += 256) {
        int bb = it / Hh, k = it - bb * Hh;
        const float* vb = h1 + ((size_t)(b0 + bb) * LL) * Hh + k;
        float acc = 0.0f;
#pragma unroll
        for (int l = 0; l < LL; ++l) acc += sAL[bb][l] * vb[l * Hh];
        sSG[it] = acc;
    }
    __syncthreads();
    // P2: s_h[bb][c] = W3b + s_l@W3T + s_g@W3T(high)
    for (int it = tid; it < BPB * Hh; it += 256) {
        int bb = it / Hh, c = it - bb * Hh;
        const float* vl = h1 + ((size_t)(b0 + bb) * LL + (LL - 1)) * Hh;
        const float* sg = sSG + bb * Hh;
        float acc = W3b[c];
#pragma unroll 4
        for (int k = 0; k < Hh; ++k) acc += vl[k] * W3T[k * Hh + c];
#pragma unroll 4
        for (int k = 0; k < Hh; ++k) acc += sg[k] * W3T[(Hh + k) * Hh + c];
        sSH[it] = acc;
    }
    __syncthreads();

    // SD A-fragments from sSH: row mm (valid < BPB), col ks*32+qq*8+e.
    short8 Sf[4];
#pragma unroll
    for (int ks = 0; ks < 4; ++ks) {
        short8 t8 = {0, 0, 0, 0, 0, 0, 0, 0};
        if (m < BPB) {
#pragma unroll
            for (int e = 0; e < 8; ++e) {
                int col = ks * 32 + quad * 8 + e;
                t8[e] = (short)f2bf(col < Hh ? sSH[m * Hh + col] : 0.0f);
            }
        }
        Sf[ks] = t8;
    }
    f32x4 accsd[GJ];
#pragma unroll
    for (int g = 0; g < GJ; ++g) {
        accsd[g] = (f32x4){0.0f, 0.0f, 0.0f, 0.0f};
#pragma unroll
        for (int ks = 0; ks < 4; ++ks)
            accsd[g] = __builtin_amdgcn_mfma_f32_16x16x32_bf16(Sf[ks], Bf[g][ks], accsd[g], 0, 0, 0);
    }

    // Preload panel b0 -> LDS buffer 0 (512 uint4)
    {
        const uint4* s4 = (const uint4*)(P + (size_t)b0 * PPAN);
        uint4 g0 = s4[tid], g1 = s4[tid + 256];
        uint4* d = (uint4*)sPan[0];
        d[tid] = g0; d[tid + 256] = g1;
    }
    __syncthreads();

    int cur = 0;
    for (int bi = 0; bi < BPB; ++bi) {
        const int b = b0 + bi;
        // Issue next-panel global loads (no wait — overlaps compute below)
        uint4 g0, g1;
        if (bi + 1 < BPB) {
            const uint4* s4 = (const uint4*)(P + (size_t)(b + 1) * PPAN);
            g0 = s4[tid]; g1 = s4[tid + 256];
        }

        const u16* sp = sPan[cur];
        f32x4 acc[GJ][2];
#pragma unroll
        for (int g = 0; g < GJ; ++g)
#pragma unroll
            for (int t = 0; t < 2; ++t)
                acc[g][t] = (f32x4){0.0f, 0.0f, 0.0f, 0.0f};
#pragma unroll
        for (int t = 0; t < 2; ++t) {
            short8 A0 = *(const short8*)&sp[(t * 4 + 0) * 512 + lane * 8];
            short8 A1 = *(const short8*)&sp[(t * 4 + 1) * 512 + lane * 8];
            short8 A2 = *(const short8*)&sp[(t * 4 + 2) * 512 + lane * 8];
            short8 A3 = *(const short8*)&sp[(t * 4 + 3) * 512 + lane * 8];
#pragma unroll
            for (int g = 0; g < GJ; ++g) {
                acc[g][t] = __builtin_amdgcn_mfma_f32_16x16x32_bf16(A0, Bf[g][0], acc[g][t], 0, 0, 0);
                acc[g][t] = __builtin_amdgcn_mfma_f32_16x16x32_bf16(A1, Bf[g][1], acc[g][t], 0, 0, 0);
                acc[g][t] = __builtin_amdgcn_mfma_f32_16x16x32_bf16(A2, Bf[g][2], acc[g][t], 0, 0, 0);
                acc[g][t] = __builtin_amdgcn_mfma_f32_16x16x32_bf16(A3, Bf[g][3], acc[g][t], 0, 0, 0);
            }
        }

        // Epilogue (max-free softmax). C/D: col=lane&15, row=quad*4+reg.
#pragma unroll
        for (int g = 0; g < GJ; ++g) {
            float den = 0.0f, num = 0.0f;
#pragma unroll
            for (int r = 0; r < 4; ++r) {
                float p = __expf(acc[g][0][r]);
                den += p;
                num += p * acc[g][1][r];
            }
            den += __shfl_xor(den, 16); num += __shfl_xor(num, 16);
            den += __shfl_xor(den, 32); num += __shfl_xor(num, 32);
            // sd for (b, j=...+m) sits in lane (bi>>2)*16+m, reg bi&3.
            f32x4 s4v = accsd[g];
            int rr = bi & 3;
            float sdv = (rr == 0) ? s4v[0] : (rr == 1) ? s4v[1] : (rr == 2) ? s4v[2] : s4v[3];
            sdv = __shfl(sdv, ((bi >> 2) << 4) | m);
            if (quad == 0) {
                int j = jb + wave * 64 + g * 16 + m;
                if (j < NNODE) {
                    float z = sdv + num / den;
                    if (bf) ((u16*)out)[(size_t)b * NNODE + j] = f2bf(z);
                    else    ((float*)out)[(size_t)b * NNODE + j] = z;
                }
            }
        }

        // Commit prefetched panel to the other buffer (vmcnt wait lands here,
        // after compute) then single barrier.
        if (bi + 1 < BPB) {
            uint4* d = (uint4*)sPan[cur ^ 1];
            d[tid] = g0; d[tid + 256] = g1;
        }
        __syncthreads();
        cur ^= 1;
    }
}

extern "C" void kernel_launch(void* const* d_in, const int* in_sizes, int n_in,
                              void* d_out, int out_size, void* d_ws, size_t ws_size,
                              hipStream_t stream) {
    const int* x      = (const int*)d_in[0];
    const int* ei     = (const int*)d_in[1];
    const void* ew    = d_in[2];
    // d_in[3] batch: unused by reference
    const void* embed = d_in[4];
    const void* ggc   = d_in[5];
    const void* wih   = d_in[6];
    const void* whh   = d_in[7];
    const void* bih   = d_in[8];
    const void* bhh   = d_in[9];
    const void* W1w   = d_in[10];
    const void* W1b   = d_in[11];
    const void* W2w   = d_in[12];
    const void* W2b   = d_in[13];
    const void* Wtw   = d_in[14];
    const void* Wtb   = d_in[15];
    const void* qw    = d_in[16];
    const void* qb    = d_in[17];
    const void* W3w   = d_in[18];
    const void* W3b   = d_in[19];
    float* ws = (float*)d_ws;
    int* flag = (int*)d_ws;          // ws[0]

    // ws layout (floats):
    //   [0..64)              flag + pad
    //   [64..64+143232)      fp32 weight region W (see cvt_impl offsets)
    //   D = ws+143296, data region:
    //     agg0 = D+0       (102400)  zeroed k_cvt, scatter2-add, read k_gruatt
    //     h1   = D+102400  (102400)  k_gruatt -> k_score prologue
    //     Q2g  = D+204800  (102400)
    //     Q1g  = D+307200  (6400)
    //     P    = (u16*)(D+313600)  131072 fl  (written k_gruatt)
    //     EB   = (u16*)(D+444672)  2080052 fl padded bf16 embed (fp32 input only)
    float* W = ws + 64;
    float* ew_f  = W + 0;
    float* ggc_f = W + 2048;
    float* wC    = W + 12048;
    float* bih_f = W + 92048;
    float* bhh_f = W + 92352;
    float* W1T   = W + 92656;
    float* W1b_f = W + 102656;
    float* W2T   = W + 102768;
    float* W2b_f = W + 112768;
    float* WtT   = W + 112880;
    float* Wtb_f = W + 122880;
    float* qw_f  = W + 122992;
    float* qb_f  = W + 123104;
    float* W3T   = W + 123120;
    float* W3b_f = W + 143120;

    float* D     = ws + 143296;
    float* agg0  = D;
    float* h1    = D + 102400;
    float* Q2g   = D + 204800;
    float* Q1g   = D + 307200;
    u16*   P     = (u16*)(D + 313600);
    u16*   EB    = (u16*)(D + 444672);

    const size_t need_bytes = (size_t)(143296 + 444672) * 4 + (size_t)(NNODE + 1) * EBS * 2;
    const bool emode = (ws_size >= need_bytes);

    // Fused cvt + (flag-gated) ecvt: blocks 0..481 = cvt (+agg0 zero),
    // 482.. = ecvt (fp32 input only; bf16 input -> early exit).
    const int ecvt_blocks = ((NNODE + 1) * (EBS / 2) + 255) / 256;   // 8126
    k_cvt    <<<dim3(emode ? 482 + ecvt_blocks : 482), dim3(256), 0, stream>>>(
                                                   embed, flag, ew, ggc, wih, whh, bih, bhh,
                                                   W1w, W1b, W2w, W2b, Wtw, Wtb, qw, qb, W3w, W3b,
                                                   W, agg0, EB);
    k_scatter2<<<dim3(EE * (Hh / 2) / 256, 1), dim3(256), 0, stream>>>(flag, ei, ew_f, x, embed, agg0);
    k_gruatt <<<dim3(NN / GRB), dim3(512), 0, stream>>>(flag, x, embed, agg0, ggc_f, wC, bih_f, bhh_f,
                                                        W1T, W1b_f, W2T, W2b_f, WtT, Wtb_f,
                                                        h1, Q2g, Q1g, P);
    if (emode)
        k_score<1><<<dim3(JBLK, BSPL), dim3(256), 0, stream>>>(flag, embed, EB, P, h1, Q1g, Q2g,
                                                               qw_f, qb_f, W3T, W3b_f, d_out);
    else
        k_score<0><<<dim3(JBLK, BSPL), dim3(256), 0, stream>>>(flag, embed, EB, P, h1, Q1g, Q2g,
                                                               qw_f, qb_f, W3T, W3b_f, d_out);
}

// Round 9
// 197.893 us; speedup vs baseline: 1.3519x; 1.3519x over previous
//
#include <hip/hip_runtime.h>
#include <hip/hip_bf16.h>

// Problem constants (from reference)
#define Hh    100
#define NN    1024     // B*L
#define BB    64
#define LL    16
#define EE    2048
#define NNODE 40000

#define BSPL  8        // b-loop split (slices)
#define BPB   (BB / BSPL)      // 8 b's per slice
#define PFR   8        // fragments per panel: f = t*4+ks, t in 0..1, ks in 0..3
#define PPAN  (PFR * 64 * 8)   // u16 per panel (4096)
#define GJ    4        // j-groups per wave (wave covers 64 embed rows)
#define EBS   104      // padded bf16 embed row stride (u16)
#define GRB   2        // rows per k_gruatt block

typedef unsigned short u16;
typedef __attribute__((ext_vector_type(8))) short short8;   // 8 bf16 = 4 VGPRs
typedef __attribute__((ext_vector_type(4))) float f32x4;    // MFMA C/D

__device__ __forceinline__ float bf2f(u16 u) {
    union { unsigned int i; float f; } v;
    v.i = ((unsigned int)u) << 16;
    return v.f;
}

__device__ __forceinline__ u16 f2bf(float f) {
    unsigned int x = __float_as_uint(f);
    unsigned int lsb = (x >> 16) & 1u;
    x += 0x7fffu + lsb;              // round-to-nearest-even
    return (u16)(x >> 16);
}

__device__ __forceinline__ float sigmoidf_(float x) {
    return 1.0f / (1.0f + expf(-x));
}

template <bool BF>
__device__ __forceinline__ float ldv(const void* p, size_t i) {
    if (BF) return bf2f(((const u16*)p)[i]);
    return ((const float*)p)[i];
}
__device__ __forceinline__ float ldvf(int flag, const void* p, size_t i) {
    return flag ? ldv<true>(p, i) : ldv<false>(p, i);
}

// ---------------------------------------------------------------------------
// k_cvt (+ gated ecvt): per-BLOCK dtype self-detect (256 embed samples —
// fp32 misdetection prob ~2^-128). Blocks 0..481: convert/transpose small
// tensors to fp32 + zero agg0/SD. Blocks 482..: embed -> padded bf16 EB,
// ONLY when input is fp32 (bf16 input: k_score reads raw embed directly;
// ks=3 tail cols are killed by zero A rows — r8 harness-verified).
template <bool BF>
__device__ void cvt_impl(int t,
                         const void* ew, const void* ggc, const void* wih, const void* whh,
                         const void* bih, const void* bhh, const void* W1w, const void* W1b,
                         const void* W2w, const void* W2b, const void* Wtw, const void* Wtb,
                         const void* qw, const void* qb, const void* W3w, const void* W3b,
                         float* __restrict__ W) {
    const void* src; int si; int doff; int di;
    if      (t <   2048) { src = ew;  si = t;          doff = 0;      di = si; }
    else if (t <  12048) { src = ggc; si = t - 2048;   doff = 2048;   di = si; }                      // row-major
    else if (t <  42048) { src = wih; si = t - 12048;  doff = 12048;  { int r = si / 100, k = si - r * 100; di = k * 800 + (r % 100) * 8 + r / 100; } }
    else if (t <  72048) { src = whh; si = t - 42048;  doff = 12048;  { int r = si / 100, k = si - r * 100; di = k * 800 + (r % 100) * 8 + 3 + r / 100; } }
    else if (t <  72348) { src = bih; si = t - 72048;  doff = 92048;  di = si; }
    else if (t <  72648) { src = bhh; si = t - 72348;  doff = 92352;  di = si; }
    else if (t <  82648) { src = W1w; si = t - 72648;  doff = 92656;  di = (si % 100) * 100 + si / 100; }   // T
    else if (t <  82748) { src = W1b; si = t - 82648;  doff = 102656; di = si; }
    else if (t <  92748) { src = W2w; si = t - 82748;  doff = 102768; di = (si % 100) * 100 + si / 100; }   // T
    else if (t <  92848) { src = W2b; si = t - 92748;  doff = 112768; di = si; }
    else if (t < 102848) { src = Wtw; si = t - 92848;  doff = 112880; di = (si % 100) * 100 + si / 100; }   // T
    else if (t < 102948) { src = Wtb; si = t - 102848; doff = 122880; di = si; }
    else if (t < 103048) { src = qw;  si = t - 102948; doff = 122992; di = si; }
    else if (t < 103049) { src = qb;  si = t - 103048; doff = 123104; di = si; }
    else if (t < 123049) { src = W3w; si = t - 103049; doff = 123120; di = (si % 200) * 100 + si / 200; }   // T
    else                 { src = W3b; si = t - 123049; doff = 143120; di = si; }
    W[doff + di] = ldv<BF>(src, si);
}

__global__ void __launch_bounds__(256) k_cvt(const void* embed_raw, int* __restrict__ flag,
                      const void* ew, const void* ggc, const void* wih, const void* whh,
                      const void* bih, const void* bhh, const void* W1w, const void* W1b,
                      const void* W2w, const void* W2b, const void* Wtw, const void* Wtb,
                      const void* qw, const void* qb, const void* W3w, const void* W3b,
                      float* __restrict__ W, float* __restrict__ agg0,
                      u16* __restrict__ SD, u16* __restrict__ EB) {
    __shared__ int cnt;
    if (threadIdx.x == 0) cnt = 0;
    __syncthreads();
    const u16* eb16 = (const u16*)embed_raw;
    {
        float v = bf2f(eb16[threadIdx.x]);
        if (!(fabsf(v) <= 0.5f)) atomicAdd(&cnt, 1);   // counts NaN too
    }
    __syncthreads();
    const bool bf = (cnt == 0);
    const int bid = blockIdx.x;
    if (bid == 0 && threadIdx.x == 0) flag[0] = bf ? 1 : 0;
    if (bid < 482) {
        int t = bid * 256 + threadIdx.x;
        if (t < NN * Hh) agg0[t] = 0.0f;             // zero scatter target
        if (t < 8192) ((unsigned int*)SD)[t] = 0u;   // zero SD (16384 u16)
        if (t >= 123149) return;
        if (bf) cvt_impl<true >(t, ew, ggc, wih, whh, bih, bhh, W1w, W1b, W2w, W2b, Wtw, Wtb, qw, qb, W3w, W3b, W);
        else    cvt_impl<false>(t, ew, ggc, wih, whh, bih, bhh, W1w, W1b, W2w, W2b, Wtw, Wtb, qw, qb, W3w, W3b, W);
    } else {
        if (bf) return;                              // bf16: EB not needed
        // ecvt (fp32 input only): embed -> padded bf16 + zeroed guard row
        int t = (bid - 482) * 256 + threadIdx.x;
        const int total = (NNODE + 1) * (EBS / 2);
        if (t >= total) return;
        int r = t / (EBS / 2), c2 = t - r * (EBS / 2);
        int k0 = c2 * 2;
        unsigned int w = 0;
        if (r < NNODE && k0 + 1 < Hh) {
            float2 e2 = *(const float2*)&((const float*)embed_raw)[(size_t)r * Hh + k0];
            w = (unsigned int)f2bf(e2.x) | ((unsigned int)f2bf(e2.y) << 16);
        }
        ((unsigned int*)EB)[t] = w;
    }
}

// ---------------------------------------------------------------------------
// k_scatter2: agg0[dst] += ew[e] * h0[src]  (h0 = embed[x[src]], gathered
// directly — the GGC GEMM is applied AFTER aggregation in k_gruatt, valid by
// linearity). 2 cols per thread (u32/float2 loads).
__global__ void k_scatter2(const int* __restrict__ flag, const int* __restrict__ ei,
                           const float* __restrict__ ew, const int* __restrict__ x,
                           const void* __restrict__ embed, float* __restrict__ agg0) {
    int t = blockIdx.x * 256 + threadIdx.x;
    if (t >= EE * (Hh / 2)) return;
    int e = t / (Hh / 2), j2 = t - e * (Hh / 2);
    int j = j2 * 2;
    int src = ei[e], dst = ei[EE + e];
    const int fl = flag[0];
    float w = ew[e];
    float h0, h1v;
    size_t base = (size_t)x[src] * Hh + j;
    if (fl) {
        unsigned int u = *(const unsigned int*)&((const u16*)embed)[base];
        h0 = bf2f((u16)(u & 0xffff));
        h1v = bf2f((u16)(u >> 16));
    } else {
        float2 f2 = *(const float2*)&((const float*)embed)[base];
        h0 = f2.x; h1v = f2.y;
    }
    atomicAdd(&agg0[dst * Hh + j], w * h0);
    atomicAdd(&agg0[dst * Hh + j + 1], w * h1v);
}

// ---------------------------------------------------------------------------
// k_gruatt v2: 512 threads/block, k-loops split 2-way (kh = tid>>8), partials
// combined in LDS. (Round-5 measured fix for latency-bound regime.)
__global__ void __launch_bounds__(512) k_gruatt(const int* __restrict__ flag,
                      const int* __restrict__ x, const void* __restrict__ embed,
                      const float* __restrict__ agg0, const float* __restrict__ ggc_f,
                      const float* __restrict__ wC,
                      const float* __restrict__ bih, const float* __restrict__ bhh,
                      const float* __restrict__ W1T, const float* __restrict__ W1b,
                      const float* __restrict__ W2T, const float* __restrict__ W2b,
                      const float* __restrict__ WtT, const float* __restrict__ Wtb,
                      float* __restrict__ h1, float* __restrict__ Q2g,
                      float* __restrict__ Q1g, u16* __restrict__ P) {
    __shared__ float sG[GRB * Hh];    // agg0 rows
    __shared__ float sH0[GRB * Hh];   // embed rows
    __shared__ float sA[GRB * Hh];    // agg rows (post-GGC)
    __shared__ float sV[GRB * Hh];    // h1 rows
    __shared__ float sVT[GRB * Hh];   // VTs rows
    __shared__ float sPx[6 * 512];    // k-split partials (stride-1 per slot)
    const int tid = threadIdx.x;
    const int r0 = blockIdx.x * GRB;
    const int fl = flag[0];
    const int kh = tid >> 8;              // k-half
    const int o  = tid & 255;             // work item (i,j)
    const bool valid = (o < GRB * Hh);
    const int i = o / Hh, j = o - i * Hh; // meaningful when valid
    const int k0 = kh * 50, k1 = k0 + 50;

    // Load agg0 + gathered embed rows (contiguous per row; coalesced).
    if (tid < GRB * Hh) {
        sG[tid] = agg0[r0 * Hh + tid];
    } else if (tid < 2 * GRB * Hh) {
        int o2 = tid - GRB * Hh;
        int i2 = o2 / Hh, j2 = o2 - i2 * Hh;
        sH0[o2] = ldvf(fl, embed, (size_t)x[r0 + i2] * Hh + j2);
    }
    __syncthreads();

    // Phase 1: agg = agg0 @ ggc (k-split partial)
    {
        float acc = 0.0f;
        if (valid) {
            const float* gi = sG + i * Hh;
#pragma unroll 5
            for (int k = k0; k < k1; ++k) acc += gi[k] * ggc_f[k * Hh + j];
        }
        sPx[tid] = acc;
    }
    __syncthreads();
    if (valid && kh == 0) sA[o] = sPx[tid] + sPx[tid + 256];
    __syncthreads();

    // Phase 2: GRU gate sums (6 accumulators, k-split)
    {
        float p0 = 0, p1 = 0, p2 = 0, p3 = 0, p4 = 0, p5 = 0;
        if (valid) {
            const float* ai = sA + i * Hh;
            const float* hi = sH0 + i * Hh;
            const float* wbase = wC + j * 8;
#pragma unroll 5
            for (int k = k0; k < k1; ++k) {
                float a = ai[k], h = hi[k];
                const float* wr = wbase + k * 800;
                float4 w0 = *(const float4*)wr;
                float2 w1 = *(const float2*)(wr + 4);
                p0 += a * w0.x;
                p1 += a * w0.y;
                p2 += a * w0.z;
                p3 += h * w0.w;
                p4 += h * w1.x;
                p5 += h * w1.y;
            }
        }
        sPx[tid] = p0;             sPx[512 + tid] = p1;
        sPx[1024 + tid] = p2;      sPx[1536 + tid] = p3;
        sPx[2048 + tid] = p4;      sPx[2560 + tid] = p5;
    }
    __syncthreads();
    if (valid && kh == 0) {
        float s_ir = bih[j] + sPx[tid] + sPx[tid + 256];
        float s_iz = bih[j + Hh] + sPx[512 + tid] + sPx[512 + tid + 256];
        float s_in = bih[j + 2 * Hh] + sPx[1024 + tid] + sPx[1024 + tid + 256];
        float s_hr = bhh[j] + sPx[1536 + tid] + sPx[1536 + tid + 256];
        float s_hz = bhh[j + Hh] + sPx[2048 + tid] + sPx[2048 + tid + 256];
        float s_hn = bhh[j + 2 * Hh] + sPx[2560 + tid] + sPx[2560 + tid + 256];
        float r = sigmoidf_(s_ir + s_hr);
        float z = sigmoidf_(s_iz + s_hz);
        float n = tanhf(s_in + r * s_hn);
        float hv = (1.0f - z) * n + z * sH0[o];
        sV[o] = hv;
        h1[r0 * Hh + o] = hv;
    }
    __syncthreads();

    // Phase 3: Q2 = h1@W2T+b, VTs = h1@WtT+b (k-split)
    {
        float a2 = 0.0f, at = 0.0f;
        if (valid) {
            const float* vi = sV + i * Hh;
#pragma unroll 5
            for (int k = k0; k < k1; ++k) {
                float vk = vi[k];
                a2 += vk * W2T[k * Hh + j];
                at += vk * WtT[k * Hh + j];
            }
        }
        sPx[tid] = a2;
        sPx[512 + tid] = at;
    }
    __syncthreads();
    if (valid && kh == 0) {
        Q2g[r0 * Hh + o] = sPx[tid] + sPx[tid + 256] + W2b[j];
        sVT[o] = sPx[512 + tid] + sPx[512 + tid + 256] + Wtb[j];
    }
    __syncthreads();

    // Q1 for session-final row (global row r0+1 == 16b+15)
    if ((r0 & 15) == 14 && tid < Hh) {
        const float* vl = sV + Hh;
        float a1 = 0.0f;
#pragma unroll 4
        for (int k = 0; k < Hh; ++k) a1 += vl[k] * W1T[k * Hh + tid];
        Q1g[(r0 >> 4) * Hh + tid] = a1 + W1b[tid];
    }
    // P fragment writes for our GRB rows, both t-tiles (t0=VTs, t1=V).
    const int b = r0 >> 4;
    if (tid < GRB * 2 * 4 * 4) {
        int ii = tid >> 5, rest = tid & 31;
        int tt = rest >> 4, ks = (rest >> 2) & 3, qq = rest & 3;
        int mm = (r0 & 15) + ii;
        int col0 = ks * 32 + qq * 8;
        const float* srow = (tt == 0 ? sVT : sV) + ii * Hh;
        short8 t8;
#pragma unroll
        for (int e = 0; e < 8; ++e) {
            int col = col0 + e;
            t8[e] = (short)f2bf(col < Hh ? srow[col] : 0.0f);
        }
        *(short8*)&P[((size_t)b * PFR + tt * 4 + ks) * 512 + (qq * 16 + mm) * 8] = t8;
    }
}

// ---------------------------------------------------------------------------
// k_att2: light per-session tail — alpha (16x16-thread shfl-reduce), s_g,
// s_h, SD row write. One block per b. SD: slice b>>3, tile row b&7 (rows
// 8..15 pre-zeroed by k_cvt).
__global__ void __launch_bounds__(256) k_att2(const float* __restrict__ h1,
                    const float* __restrict__ Q1g, const float* __restrict__ Q2g,
                    const float* __restrict__ qw, const float* __restrict__ qb,
                    const float* __restrict__ W3T, const float* __restrict__ W3b,
                    u16* __restrict__ SD) {
    __shared__ float V[LL * Hh];
    __shared__ float AL[LL];
    __shared__ float SG[Hh];
    __shared__ float SH[Hh];
    const int b = blockIdx.x, tid = threadIdx.x;
    for (int o = tid; o < LL * Hh; o += 256) V[o] = h1[b * LL * Hh + o];
    __syncthreads();
    {
        int l = tid >> 4, t = tid & 15;
        float acc = 0.0f;
        for (int j = t; j < Hh; j += 16)
            acc += sigmoidf_(Q1g[b * Hh + j] + Q2g[(b * LL + l) * Hh + j]) * qw[j];
        acc += __shfl_xor(acc, 8);
        acc += __shfl_xor(acc, 4);
        acc += __shfl_xor(acc, 2);
        acc += __shfl_xor(acc, 1);
        if (t == 0) AL[l] = acc + qb[0];
    }
    __syncthreads();
    if (tid < Hh) {
        float acc = 0.0f;
#pragma unroll
        for (int l = 0; l < LL; ++l) acc += AL[l] * V[l * Hh + tid];
        SG[tid] = acc;
    }
    __syncthreads();
    if (tid < Hh) {
        float acc = W3b[tid];
#pragma unroll 4
        for (int k = 0; k < Hh; ++k) acc += V[(LL - 1) * Hh + k] * W3T[k * Hh + tid];
#pragma unroll 4
        for (int k = 0; k < Hh; ++k) acc += SG[k] * W3T[(Hh + k) * Hh + tid];
        SH[tid] = acc;
    }
    __syncthreads();
    // SD write: A-tile row (b&7) of slice (b>>3); 128 u16 scattered.
    if (tid < 128) {
        int ks = tid >> 5, qq = (tid >> 3) & 3, e = tid & 7;
        int col = ks * 32 + qq * 8 + e;
        float v = (col < Hh) ? SH[col] : 0.0f;
        SD[(((size_t)(b >> 3) * 4 + ks) * 64 + qq * 16 + (b & 7)) * 8 + e] = f2bf(v);
    }
}

// ---------------------------------------------------------------------------
// k_score v13 = v11 (r7, measured-good) + uniform dtype branch for B-frags:
// bf16 input -> raw embed loads (EB conversion skipped entirely; r8-verified),
// fp32 -> EB. BSPL=8, GJ=4, SD prologue, LDS panel double-buffer with
// register prefetch, one barrier/iter, max-free softmax.
__device__ __forceinline__ short8 load_efrag(const void* embed, bool bf, int j, int k0) {
    short8 v = {0, 0, 0, 0, 0, 0, 0, 0};
    if (j >= NNODE || k0 >= Hh) return v;
    if (bf) {
        const u16* row = (const u16*)embed + (size_t)j * Hh + k0;
        if (k0 + 8 <= Hh) {
            ushort4 a = *(const ushort4*)(row);
            ushort4 b = *(const ushort4*)(row + 4);
            v[0] = (short)a.x; v[1] = (short)a.y; v[2] = (short)a.z; v[3] = (short)a.w;
            v[4] = (short)b.x; v[5] = (short)b.y; v[6] = (short)b.z; v[7] = (short)b.w;
        } else {
            for (int e = 0; e < Hh - k0; ++e) v[e] = (short)row[e];
        }
    } else {
        const float* row = (const float*)embed + (size_t)j * Hh + k0;
        if (k0 + 8 <= Hh) {
            float4 a = *(const float4*)(row);
            float4 b = *(const float4*)(row + 4);
            v[0] = (short)f2bf(a.x); v[1] = (short)f2bf(a.y); v[2] = (short)f2bf(a.z); v[3] = (short)f2bf(a.w);
            v[4] = (short)f2bf(b.x); v[5] = (short)f2bf(b.y); v[6] = (short)f2bf(b.z); v[7] = (short)f2bf(b.w);
        } else {
            for (int e = 0; e < Hh - k0; ++e) v[e] = (short)f2bf(row[e]);
        }
    }
    return v;
}

#define JBLK  157   // ceil(40000/256)

template <int EMODE>
__global__ void __launch_bounds__(256) k_score(const int* __restrict__ flag,
                                               const void* __restrict__ embed,
                                               const u16* __restrict__ EB,
                                               const u16* __restrict__ P,
                                               const u16* __restrict__ SD,
                                               void* __restrict__ out) {
    __shared__ alignas(16) u16 sPan[2][PPAN];    // 2 x 8192 B
    const int jb = blockIdx.x * 256;
    const int slice = blockIdx.y;
    const int b0 = slice * BPB;
    const int tid = threadIdx.x;
    const bool bf = (flag[0] != 0);
    const int wave = tid >> 6, lane = tid & 63;
    const int m = lane & 15, quad = lane >> 4;

    // B fragments: 4 groups of 16 embed rows per wave, loaded once.
    // Uniform branch on dtype: bf16 -> raw embed; fp32 -> EB (if EMODE).
    short8 Bf[GJ][4];
#pragma unroll
    for (int g = 0; g < GJ; ++g)
#pragma unroll
        for (int ks = 0; ks < 4; ++ks) {
            int j = jb + wave * 64 + g * 16 + m;
            if (bf) {
                Bf[g][ks] = load_efrag(embed, true, j, ks * 32 + quad * 8);
            } else if (EMODE) {
                short8 v = {0, 0, 0, 0, 0, 0, 0, 0};
                if (j < NNODE)
                    v = *(const short8*)&EB[(size_t)j * EBS + ks * 32 + quad * 8];
                Bf[g][ks] = v;
            } else {
                Bf[g][ks] = load_efrag(embed, false, j, ks * 32 + quad * 8);
            }
        }

    // SD prologue: sd[b0+r][j] for the 8 b's of this slice, 16 MFMAs.
    short8 Sf[4];
#pragma unroll
    for (int ks = 0; ks < 4; ++ks)
        Sf[ks] = *(const short8*)&SD[(((size_t)slice * 4 + ks) * 64 + lane) * 8];
    f32x4 accsd[GJ];
#pragma unroll
    for (int g = 0; g < GJ; ++g) {
        accsd[g] = (f32x4){0.0f, 0.0f, 0.0f, 0.0f};
#pragma unroll
        for (int ks = 0; ks < 4; ++ks)
            accsd[g] = __builtin_amdgcn_mfma_f32_16x16x32_bf16(Sf[ks], Bf[g][ks], accsd[g], 0, 0, 0);
    }

    // Preload panel b0 -> LDS buffer 0 (512 uint4)
    {
        const uint4* s4 = (const uint4*)(P + (size_t)b0 * PPAN);
        uint4 g0 = s4[tid], g1 = s4[tid + 256];
        uint4* d = (uint4*)sPan[0];
        d[tid] = g0; d[tid + 256] = g1;
    }
    __syncthreads();

    int cur = 0;
    for (int bi = 0; bi < BPB; ++bi) {
        const int b = b0 + bi;
        // Issue next-panel global loads (no wait — overlaps compute below)
        uint4 g0, g1;
        if (bi + 1 < BPB) {
            const uint4* s4 = (const uint4*)(P + (size_t)(b + 1) * PPAN);
            g0 = s4[tid]; g1 = s4[tid + 256];
        }

        const u16* sp = sPan[cur];
        f32x4 acc[GJ][2];
#pragma unroll
        for (int g = 0; g < GJ; ++g)
#pragma unroll
            for (int t = 0; t < 2; ++t)
                acc[g][t] = (f32x4){0.0f, 0.0f, 0.0f, 0.0f};
#pragma unroll
        for (int t = 0; t < 2; ++t) {
            short8 A0 = *(const short8*)&sp[(t * 4 + 0) * 512 + lane * 8];
            short8 A1 = *(const short8*)&sp[(t * 4 + 1) * 512 + lane * 8];
            short8 A2 = *(const short8*)&sp[(t * 4 + 2) * 512 + lane * 8];
            short8 A3 = *(const short8*)&sp[(t * 4 + 3) * 512 + lane * 8];
#pragma unroll
            for (int g = 0; g < GJ; ++g) {
                acc[g][t] = __builtin_amdgcn_mfma_f32_16x16x32_bf16(A0, Bf[g][0], acc[g][t], 0, 0, 0);
                acc[g][t] = __builtin_amdgcn_mfma_f32_16x16x32_bf16(A1, Bf[g][1], acc[g][t], 0, 0, 0);
                acc[g][t] = __builtin_amdgcn_mfma_f32_16x16x32_bf16(A2, Bf[g][2], acc[g][t], 0, 0, 0);
                acc[g][t] = __builtin_amdgcn_mfma_f32_16x16x32_bf16(A3, Bf[g][3], acc[g][t], 0, 0, 0);
            }
        }

        // Epilogue (max-free softmax). C/D: col=lane&15, row=quad*4+reg.
#pragma unroll
        for (int g = 0; g < GJ; ++g) {
            float den = 0.0f, num = 0.0f;
#pragma unroll
            for (int r = 0; r < 4; ++r) {
                float p = __expf(acc[g][0][r]);
                den += p;
                num += p * acc[g][1][r];
            }
            den += __shfl_xor(den, 16); num += __shfl_xor(num, 16);
            den += __shfl_xor(den, 32); num += __shfl_xor(num, 32);
            // sd for (b, j=...+m) sits in lane (bi>>2)*16+m, reg bi&3.
            f32x4 s4v = accsd[g];
            int rr = bi & 3;
            float sdv = (rr == 0) ? s4v[0] : (rr == 1) ? s4v[1] : (rr == 2) ? s4v[2] : s4v[3];
            sdv = __shfl(sdv, ((bi >> 2) << 4) | m);
            if (quad == 0) {
                int j = jb + wave * 64 + g * 16 + m;
                if (j < NNODE) {
                    float z = sdv + num / den;
                    if (bf) ((u16*)out)[(size_t)b * NNODE + j] = f2bf(z);
                    else    ((float*)out)[(size_t)b * NNODE + j] = z;
                }
            }
        }

        // Commit prefetched panel to the other buffer (vmcnt wait lands here,
        // after compute) then single barrier.
        if (bi + 1 < BPB) {
            uint4* d = (uint4*)sPan[cur ^ 1];
            d[tid] = g0; d[tid + 256] = g1;
        }
        __syncthreads();
        cur ^= 1;
    }
}

extern "C" void kernel_launch(void* const* d_in, const int* in_sizes, int n_in,
                              void* d_out, int out_size, void* d_ws, size_t ws_size,
                              hipStream_t stream) {
    const int* x      = (const int*)d_in[0];
    const int* ei     = (const int*)d_in[1];
    const void* ew    = d_in[2];
    // d_in[3] batch: unused by reference
    const void* embed = d_in[4];
    const void* ggc   = d_in[5];
    const void* wih   = d_in[6];
    const void* whh   = d_in[7];
    const void* bih   = d_in[8];
    const void* bhh   = d_in[9];
    const void* W1w   = d_in[10];
    const void* W1b   = d_in[11];
    const void* W2w   = d_in[12];
    const void* W2b   = d_in[13];
    const void* Wtw   = d_in[14];
    const void* Wtb   = d_in[15];
    const void* qw    = d_in[16];
    const void* qb    = d_in[17];
    const void* W3w   = d_in[18];
    const void* W3b   = d_in[19];
    float* ws = (float*)d_ws;
    int* flag = (int*)d_ws;          // ws[0]

    // ws layout (floats):
    //   [0..64)              flag + pad
    //   [64..64+143232)      fp32 weight region W (see cvt_impl offsets)
    //   D = ws+143296, data region:
    //     agg0 = D+0       (102400)  zeroed k_cvt, scatter2-add, read k_gruatt
    //     h1   = D+102400  (102400)  k_gruatt -> k_att2
    //     Q2g  = D+204800  (102400)
    //     Q1g  = D+307200  (6400)
    //     P    = (u16*)(D+313600)  131072 fl  (written k_gruatt)
    //     SD   = (u16*)(D+444672)  8192 fl    (zeroed k_cvt, rows via k_att2)
    //     EB   = (u16*)(D+452864)  2080052 fl padded bf16 embed (fp32 input only)
    float* W = ws + 64;
    float* ew_f  = W + 0;
    float* ggc_f = W + 2048;
    float* wC    = W + 12048;
    float* bih_f = W + 92048;
    float* bhh_f = W + 92352;
    float* W1T   = W + 92656;
    float* W1b_f = W + 102656;
    float* W2T   = W + 102768;
    float* W2b_f = W + 112768;
    float* WtT   = W + 112880;
    float* Wtb_f = W + 122880;
    float* qw_f  = W + 122992;
    float* qb_f  = W + 123104;
    float* W3T   = W + 123120;
    float* W3b_f = W + 143120;

    float* D     = ws + 143296;
    float* agg0  = D;
    float* h1    = D + 102400;
    float* Q2g   = D + 204800;
    float* Q1g   = D + 307200;
    u16*   P     = (u16*)(D + 313600);
    u16*   SDp   = (u16*)(D + 444672);
    u16*   EB    = (u16*)(D + 452864);

    const size_t need_bytes = (size_t)(143296 + 452864) * 4 + (size_t)(NNODE + 1) * EBS * 2;
    const bool emode = (ws_size >= need_bytes);

    // Fused cvt + (flag-gated) ecvt: blocks 0..481 = cvt (+agg0/SD zero),
    // 482.. = ecvt (fp32 input only; bf16 input -> early exit).
    const int ecvt_blocks = ((NNODE + 1) * (EBS / 2) + 255) / 256;   // 8126
    k_cvt    <<<dim3(emode ? 482 + ecvt_blocks : 482), dim3(256), 0, stream>>>(
                                                   embed, flag, ew, ggc, wih, whh, bih, bhh,
                                                   W1w, W1b, W2w, W2b, Wtw, Wtb, qw, qb, W3w, W3b,
                                                   W, agg0, SDp, EB);
    k_scatter2<<<dim3(EE * (Hh / 2) / 256, 1), dim3(256), 0, stream>>>(flag, ei, ew_f, x, embed, agg0);
    k_gruatt <<<dim3(NN / GRB), dim3(512), 0, stream>>>(flag, x, embed, agg0, ggc_f, wC, bih_f, bhh_f,
                                                        W1T, W1b_f, W2T, W2b_f, WtT, Wtb_f,
                                                        h1, Q2g, Q1g, P);
    k_att2   <<<dim3(BB), dim3(256), 0, stream>>>(h1, Q1g, Q2g, qw_f, qb_f, W3T, W3b_f, SDp);
    if (emode)
        k_score<1><<<dim3(JBLK, BSPL), dim3(256), 0, stream>>>(flag, embed, EB, P, SDp, d_out);
    else
        k_score<0><<<dim3(JBLK, BSPL), dim3(256), 0, stream>>>(flag, embed, EB, P, SDp, d_out);
}

// Round 10
// 194.189 us; speedup vs baseline: 1.3777x; 1.0191x over previous
//
#include <hip/hip_runtime.h>
#include <hip/hip_bf16.h>

// Problem constants (from reference)
#define Hh    100
#define NN    1024     // B*L
#define BB    64
#define LL    16
#define EE    2048
#define NNODE 40000

#define BSPL  8        // b-loop split (slices)
#define BPB   (BB / BSPL)      // 8 b's per slice
#define PFR   8        // fragments per panel: f = t*4+ks, t in 0..1, ks in 0..3
#define PPAN  (PFR * 64 * 8)   // u16 per panel (4096)
#define GJ    4        // j-groups per wave (wave covers 64 embed rows)
#define EBS   104      // padded bf16 embed row stride (u16)
#define GRB   2        // rows per k_gruatt block

typedef unsigned short u16;
typedef __attribute__((ext_vector_type(8))) short short8;   // 8 bf16 = 4 VGPRs
typedef __attribute__((ext_vector_type(4))) float f32x4;    // MFMA C/D

__device__ __forceinline__ float bf2f(u16 u) {
    union { unsigned int i; float f; } v;
    v.i = ((unsigned int)u) << 16;
    return v.f;
}

__device__ __forceinline__ u16 f2bf(float f) {
    unsigned int x = __float_as_uint(f);
    unsigned int lsb = (x >> 16) & 1u;
    x += 0x7fffu + lsb;              // round-to-nearest-even
    return (u16)(x >> 16);
}

__device__ __forceinline__ float sigmoidf_(float x) {
    return 1.0f / (1.0f + expf(-x));
}

template <bool BF>
__device__ __forceinline__ float ldv(const void* p, size_t i) {
    if (BF) return bf2f(((const u16*)p)[i]);
    return ((const float*)p)[i];
}
__device__ __forceinline__ float ldvf(int flag, const void* p, size_t i) {
    return flag ? ldv<true>(p, i) : ldv<false>(p, i);
}

// ---------------------------------------------------------------------------
// k_cvt (fused with ecvt, UNCONDITIONAL — r9 measured: EB's 208-stride gives
// aligned 16B fragment loads, worth more than the conversion costs even for
// bf16 input). Per-BLOCK dtype self-detect (fp32 misdetect prob ~2^-128).
// Blocks 0..481: convert/transpose small tensors + zero agg0/SD.
// Blocks 482..: embed -> padded bf16 EB + zeroed guard row.
template <bool BF>
__device__ void cvt_impl(int t,
                         const void* ew, const void* ggc, const void* wih, const void* whh,
                         const void* bih, const void* bhh, const void* W1w, const void* W1b,
                         const void* W2w, const void* W2b, const void* Wtw, const void* Wtb,
                         const void* qw, const void* qb, const void* W3w, const void* W3b,
                         float* __restrict__ W) {
    const void* src; int si; int doff; int di;
    if      (t <   2048) { src = ew;  si = t;          doff = 0;      di = si; }
    else if (t <  12048) { src = ggc; si = t - 2048;   doff = 2048;   di = si; }                      // row-major
    else if (t <  42048) { src = wih; si = t - 12048;  doff = 12048;  { int r = si / 100, k = si - r * 100; di = k * 800 + (r % 100) * 8 + r / 100; } }
    else if (t <  72048) { src = whh; si = t - 42048;  doff = 12048;  { int r = si / 100, k = si - r * 100; di = k * 800 + (r % 100) * 8 + 3 + r / 100; } }
    else if (t <  72348) { src = bih; si = t - 72048;  doff = 92048;  di = si; }
    else if (t <  72648) { src = bhh; si = t - 72348;  doff = 92352;  di = si; }
    else if (t <  82648) { src = W1w; si = t - 72648;  doff = 92656;  di = (si % 100) * 100 + si / 100; }   // T
    else if (t <  82748) { src = W1b; si = t - 82648;  doff = 102656; di = si; }
    else if (t <  92748) { src = W2w; si = t - 82748;  doff = 102768; di = (si % 100) * 100 + si / 100; }   // T
    else if (t <  92848) { src = W2b; si = t - 92748;  doff = 112768; di = si; }
    else if (t < 102848) { src = Wtw; si = t - 92848;  doff = 112880; di = (si % 100) * 100 + si / 100; }   // T
    else if (t < 102948) { src = Wtb; si = t - 102848; doff = 122880; di = si; }
    else if (t < 103048) { src = qw;  si = t - 102948; doff = 122992; di = si; }
    else if (t < 103049) { src = qb;  si = t - 103048; doff = 123104; di = si; }
    else if (t < 123049) { src = W3w; si = t - 103049; doff = 123120; di = (si % 200) * 100 + si / 200; }   // T
    else                 { src = W3b; si = t - 123049; doff = 143120; di = si; }
    W[doff + di] = ldv<BF>(src, si);
}

__global__ void __launch_bounds__(256) k_cvt(const void* embed_raw, int* __restrict__ flag,
                      const void* ew, const void* ggc, const void* wih, const void* whh,
                      const void* bih, const void* bhh, const void* W1w, const void* W1b,
                      const void* W2w, const void* W2b, const void* Wtw, const void* Wtb,
                      const void* qw, const void* qb, const void* W3w, const void* W3b,
                      float* __restrict__ W, float* __restrict__ agg0,
                      u16* __restrict__ SD, u16* __restrict__ EB) {
    __shared__ int cnt;
    if (threadIdx.x == 0) cnt = 0;
    __syncthreads();
    const u16* eb16 = (const u16*)embed_raw;
    {
        float v = bf2f(eb16[threadIdx.x]);
        if (!(fabsf(v) <= 0.5f)) atomicAdd(&cnt, 1);   // counts NaN too
    }
    __syncthreads();
    const bool bf = (cnt == 0);
    const int bid = blockIdx.x;
    if (bid == 0 && threadIdx.x == 0) flag[0] = bf ? 1 : 0;
    if (bid < 482) {
        int t = bid * 256 + threadIdx.x;
        if (t < NN * Hh) agg0[t] = 0.0f;             // zero scatter target
        if (t < 8192) ((unsigned int*)SD)[t] = 0u;   // zero SD (16384 u16)
        if (t >= 123149) return;
        if (bf) cvt_impl<true >(t, ew, ggc, wih, whh, bih, bhh, W1w, W1b, W2w, W2b, Wtw, Wtb, qw, qb, W3w, W3b, W);
        else    cvt_impl<false>(t, ew, ggc, wih, whh, bih, bhh, W1w, W1b, W2w, W2b, Wtw, Wtb, qw, qb, W3w, W3b, W);
    } else {
        // ecvt: embed -> padded bf16 (stride EBS, cols 100..103 = 0) + guard row
        int t = (bid - 482) * 256 + threadIdx.x;
        const int total = (NNODE + 1) * (EBS / 2);
        if (t >= total) return;
        int r = t / (EBS / 2), c2 = t - r * (EBS / 2);
        int k0 = c2 * 2;
        unsigned int w = 0;
        if (r < NNODE && k0 + 1 < Hh) {
            if (bf) {
                w = *(const unsigned int*)&((const u16*)embed_raw)[(size_t)r * Hh + k0];
            } else {
                float2 e2 = *(const float2*)&((const float*)embed_raw)[(size_t)r * Hh + k0];
                w = (unsigned int)f2bf(e2.x) | ((unsigned int)f2bf(e2.y) << 16);
            }
        }
        ((unsigned int*)EB)[t] = w;
    }
}

// ---------------------------------------------------------------------------
// k_scatter2: agg0[dst] += ew[e] * h0[src]  (h0 = embed[x[src]], gathered
// directly — the GGC GEMM is applied AFTER aggregation in k_gruatt, valid by
// linearity). 2 cols per thread (u32/float2 loads).
__global__ void k_scatter2(const int* __restrict__ flag, const int* __restrict__ ei,
                           const float* __restrict__ ew, const int* __restrict__ x,
                           const void* __restrict__ embed, float* __restrict__ agg0) {
    int t = blockIdx.x * 256 + threadIdx.x;
    if (t >= EE * (Hh / 2)) return;
    int e = t / (Hh / 2), j2 = t - e * (Hh / 2);
    int j = j2 * 2;
    int src = ei[e], dst = ei[EE + e];
    const int fl = flag[0];
    float w = ew[e];
    float h0, h1v;
    size_t base = (size_t)x[src] * Hh + j;
    if (fl) {
        unsigned int u = *(const unsigned int*)&((const u16*)embed)[base];
        h0 = bf2f((u16)(u & 0xffff));
        h1v = bf2f((u16)(u >> 16));
    } else {
        float2 f2 = *(const float2*)&((const float*)embed)[base];
        h0 = f2.x; h1v = f2.y;
    }
    atomicAdd(&agg0[dst * Hh + j], w * h0);
    atomicAdd(&agg0[dst * Hh + j + 1], w * h1v);
}

// ---------------------------------------------------------------------------
// k_gruatt v2: 512 threads/block, k-loops split 2-way (kh = tid>>8), partials
// combined in LDS. (Round-5 measured fix for latency-bound regime.)
__global__ void __launch_bounds__(512) k_gruatt(const int* __restrict__ flag,
                      const int* __restrict__ x, const void* __restrict__ embed,
                      const float* __restrict__ agg0, const float* __restrict__ ggc_f,
                      const float* __restrict__ wC,
                      const float* __restrict__ bih, const float* __restrict__ bhh,
                      const float* __restrict__ W1T, const float* __restrict__ W1b,
                      const float* __restrict__ W2T, const float* __restrict__ W2b,
                      const float* __restrict__ WtT, const float* __restrict__ Wtb,
                      float* __restrict__ h1, float* __restrict__ Q2g,
                      float* __restrict__ Q1g, u16* __restrict__ P) {
    __shared__ float sG[GRB * Hh];    // agg0 rows
    __shared__ float sH0[GRB * Hh];   // embed rows
    __shared__ float sA[GRB * Hh];    // agg rows (post-GGC)
    __shared__ float sV[GRB * Hh];    // h1 rows
    __shared__ float sVT[GRB * Hh];   // VTs rows
    __shared__ float sPx[6 * 512];    // k-split partials (stride-1 per slot)
    const int tid = threadIdx.x;
    const int r0 = blockIdx.x * GRB;
    const int fl = flag[0];
    const int kh = tid >> 8;              // k-half
    const int o  = tid & 255;             // work item (i,j)
    const bool valid = (o < GRB * Hh);
    const int i = o / Hh, j = o - i * Hh; // meaningful when valid
    const int k0 = kh * 50, k1 = k0 + 50;

    // Load agg0 + gathered embed rows (contiguous per row; coalesced).
    if (tid < GRB * Hh) {
        sG[tid] = agg0[r0 * Hh + tid];
    } else if (tid < 2 * GRB * Hh) {
        int o2 = tid - GRB * Hh;
        int i2 = o2 / Hh, j2 = o2 - i2 * Hh;
        sH0[o2] = ldvf(fl, embed, (size_t)x[r0 + i2] * Hh + j2);
    }
    __syncthreads();

    // Phase 1: agg = agg0 @ ggc (k-split partial)
    {
        float acc = 0.0f;
        if (valid) {
            const float* gi = sG + i * Hh;
#pragma unroll 5
            for (int k = k0; k < k1; ++k) acc += gi[k] * ggc_f[k * Hh + j];
        }
        sPx[tid] = acc;
    }
    __syncthreads();
    if (valid && kh == 0) sA[o] = sPx[tid] + sPx[tid + 256];
    __syncthreads();

    // Phase 2: GRU gate sums (6 accumulators, k-split)
    {
        float p0 = 0, p1 = 0, p2 = 0, p3 = 0, p4 = 0, p5 = 0;
        if (valid) {
            const float* ai = sA + i * Hh;
            const float* hi = sH0 + i * Hh;
            const float* wbase = wC + j * 8;
#pragma unroll 5
            for (int k = k0; k < k1; ++k) {
                float a = ai[k], h = hi[k];
                const float* wr = wbase + k * 800;
                float4 w0 = *(const float4*)wr;
                float2 w1 = *(const float2*)(wr + 4);
                p0 += a * w0.x;
                p1 += a * w0.y;
                p2 += a * w0.z;
                p3 += h * w0.w;
                p4 += h * w1.x;
                p5 += h * w1.y;
            }
        }
        sPx[tid] = p0;             sPx[512 + tid] = p1;
        sPx[1024 + tid] = p2;      sPx[1536 + tid] = p3;
        sPx[2048 + tid] = p4;      sPx[2560 + tid] = p5;
    }
    __syncthreads();
    if (valid && kh == 0) {
        float s_ir = bih[j] + sPx[tid] + sPx[tid + 256];
        float s_iz = bih[j + Hh] + sPx[512 + tid] + sPx[512 + tid + 256];
        float s_in = bih[j + 2 * Hh] + sPx[1024 + tid] + sPx[1024 + tid + 256];
        float s_hr = bhh[j] + sPx[1536 + tid] + sPx[1536 + tid + 256];
        float s_hz = bhh[j + Hh] + sPx[2048 + tid] + sPx[2048 + tid + 256];
        float s_hn = bhh[j + 2 * Hh] + sPx[2560 + tid] + sPx[2560 + tid + 256];
        float r = sigmoidf_(s_ir + s_hr);
        float z = sigmoidf_(s_iz + s_hz);
        float n = tanhf(s_in + r * s_hn);
        float hv = (1.0f - z) * n + z * sH0[o];
        sV[o] = hv;
        h1[r0 * Hh + o] = hv;
    }
    __syncthreads();

    // Phase 3: Q2 = h1@W2T+b, VTs = h1@WtT+b (k-split)
    {
        float a2 = 0.0f, at = 0.0f;
        if (valid) {
            const float* vi = sV + i * Hh;
#pragma unroll 5
            for (int k = k0; k < k1; ++k) {
                float vk = vi[k];
                a2 += vk * W2T[k * Hh + j];
                at += vk * WtT[k * Hh + j];
            }
        }
        sPx[tid] = a2;
        sPx[512 + tid] = at;
    }
    __syncthreads();
    if (valid && kh == 0) {
        Q2g[r0 * Hh + o] = sPx[tid] + sPx[tid + 256] + W2b[j];
        sVT[o] = sPx[512 + tid] + sPx[512 + tid + 256] + Wtb[j];
    }
    __syncthreads();

    // Q1 for session-final row (global row r0+1 == 16b+15)
    if ((r0 & 15) == 14 && tid < Hh) {
        const float* vl = sV + Hh;
        float a1 = 0.0f;
#pragma unroll 4
        for (int k = 0; k < Hh; ++k) a1 += vl[k] * W1T[k * Hh + tid];
        Q1g[(r0 >> 4) * Hh + tid] = a1 + W1b[tid];
    }
    // P fragment writes for our GRB rows, both t-tiles (t0=VTs, t1=V).
    const int b = r0 >> 4;
    if (tid < GRB * 2 * 4 * 4) {
        int ii = tid >> 5, rest = tid & 31;
        int tt = rest >> 4, ks = (rest >> 2) & 3, qq = rest & 3;
        int mm = (r0 & 15) + ii;
        int col0 = ks * 32 + qq * 8;
        const float* srow = (tt == 0 ? sVT : sV) + ii * Hh;
        short8 t8;
#pragma unroll
        for (int e = 0; e < 8; ++e) {
            int col = col0 + e;
            t8[e] = (short)f2bf(col < Hh ? srow[col] : 0.0f);
        }
        *(short8*)&P[((size_t)b * PFR + tt * 4 + ks) * 512 + (qq * 16 + mm) * 8] = t8;
    }
}

// ---------------------------------------------------------------------------
// k_att2: light per-session tail — alpha (16x16-thread shfl-reduce), s_g,
// s_h, SD row write. One block per b. SD: slice b>>3, tile row b&7 (rows
// 8..15 pre-zeroed by k_cvt).
__global__ void __launch_bounds__(256) k_att2(const float* __restrict__ h1,
                    const float* __restrict__ Q1g, const float* __restrict__ Q2g,
                    const float* __restrict__ qw, const float* __restrict__ qb,
                    const float* __restrict__ W3T, const float* __restrict__ W3b,
                    u16* __restrict__ SD) {
    __shared__ float V[LL * Hh];
    __shared__ float AL[LL];
    __shared__ float SG[Hh];
    __shared__ float SH[Hh];
    const int b = blockIdx.x, tid = threadIdx.x;
    for (int o = tid; o < LL * Hh; o += 256) V[o] = h1[b * LL * Hh + o];
    __syncthreads();
    {
        int l = tid >> 4, t = tid & 15;
        float acc = 0.0f;
        for (int j = t; j < Hh; j += 16)
            acc += sigmoidf_(Q1g[b * Hh + j] + Q2g[(b * LL + l) * Hh + j]) * qw[j];
        acc += __shfl_xor(acc, 8);
        acc += __shfl_xor(acc, 4);
        acc += __shfl_xor(acc, 2);
        acc += __shfl_xor(acc, 1);
        if (t == 0) AL[l] = acc + qb[0];
    }
    __syncthreads();
    if (tid < Hh) {
        float acc = 0.0f;
#pragma unroll
        for (int l = 0; l < LL; ++l) acc += AL[l] * V[l * Hh + tid];
        SG[tid] = acc;
    }
    __syncthreads();
    if (tid < Hh) {
        float acc = W3b[tid];
#pragma unroll 4
        for (int k = 0; k < Hh; ++k) acc += V[(LL - 1) * Hh + k] * W3T[k * Hh + tid];
#pragma unroll 4
        for (int k = 0; k < Hh; ++k) acc += SG[k] * W3T[(Hh + k) * Hh + tid];
        SH[tid] = acc;
    }
    __syncthreads();
    // SD write: A-tile row (b&7) of slice (b>>3); 128 u16 scattered.
    if (tid < 128) {
        int ks = tid >> 5, qq = (tid >> 3) & 3, e = tid & 7;
        int col = ks * 32 + qq * 8 + e;
        float v = (col < Hh) ? SH[col] : 0.0f;
        SD[(((size_t)(b >> 3) * 4 + ks) * 64 + qq * 16 + (b & 7)) * 8 + e] = f2bf(v);
    }
}

// ---------------------------------------------------------------------------
// k_score v14 = v11 (r7, EB fragment loads — r9 A/B: EB path ~10 µs faster
// than raw due to aligned 16B loads) + 2-panels-per-iteration: 4 barriers
// instead of 8 (r6/r9 counters: latency/barrier-bound, both pipes <40%).
// LDS 2 x 16KB double-buffer -> still 5 blocks/CU at grid 4.9.
__device__ __forceinline__ short8 load_efrag(const void* embed, bool bf, int j, int k0) {
    short8 v = {0, 0, 0, 0, 0, 0, 0, 0};
    if (j >= NNODE || k0 >= Hh) return v;
    if (bf) {
        const u16* row = (const u16*)embed + (size_t)j * Hh + k0;
        if (k0 + 8 <= Hh) {
            ushort4 a = *(const ushort4*)(row);
            ushort4 b = *(const ushort4*)(row + 4);
            v[0] = (short)a.x; v[1] = (short)a.y; v[2] = (short)a.z; v[3] = (short)a.w;
            v[4] = (short)b.x; v[5] = (short)b.y; v[6] = (short)b.z; v[7] = (short)b.w;
        } else {
            for (int e = 0; e < Hh - k0; ++e) v[e] = (short)row[e];
        }
    } else {
        const float* row = (const float*)embed + (size_t)j * Hh + k0;
        if (k0 + 8 <= Hh) {
            float4 a = *(const float4*)(row);
            float4 b = *(const float4*)(row + 4);
            v[0] = (short)f2bf(a.x); v[1] = (short)f2bf(a.y); v[2] = (short)f2bf(a.z); v[3] = (short)f2bf(a.w);
            v[4] = (short)f2bf(b.x); v[5] = (short)f2bf(b.y); v[6] = (short)f2bf(b.z); v[7] = (short)f2bf(b.w);
        } else {
            for (int e = 0; e < Hh - k0; ++e) v[e] = (short)f2bf(row[e]);
        }
    }
    return v;
}

#define JBLK  157   // ceil(40000/256)

template <int EMODE>
__global__ void __launch_bounds__(256) k_score(const int* __restrict__ flag,
                                               const void* __restrict__ embed,
                                               const u16* __restrict__ EB,
                                               const u16* __restrict__ P,
                                               const u16* __restrict__ SD,
                                               void* __restrict__ out) {
    __shared__ alignas(16) u16 sPan[2][2 * PPAN];    // 2 x 16384 B
    const int jb = blockIdx.x * 256;
    const int slice = blockIdx.y;
    const int b0 = slice * BPB;
    const int tid = threadIdx.x;
    const bool bf = (flag[0] != 0);
    const int wave = tid >> 6, lane = tid & 63;
    const int m = lane & 15, quad = lane >> 4;

    // B fragments: 4 groups of 16 embed rows per wave, loaded once.
    short8 Bf[GJ][4];
#pragma unroll
    for (int g = 0; g < GJ; ++g)
#pragma unroll
        for (int ks = 0; ks < 4; ++ks) {
            int j = jb + wave * 64 + g * 16 + m;
            if (EMODE) {
                short8 v = {0, 0, 0, 0, 0, 0, 0, 0};
                if (j < NNODE)
                    v = *(const short8*)&EB[(size_t)j * EBS + ks * 32 + quad * 8];
                Bf[g][ks] = v;
            } else {
                Bf[g][ks] = load_efrag(embed, bf, j, ks * 32 + quad * 8);
            }
        }

    // SD prologue: sd[b0+r][j] for the 8 b's of this slice, 16 MFMAs.
    short8 Sf[4];
#pragma unroll
    for (int ks = 0; ks < 4; ++ks)
        Sf[ks] = *(const short8*)&SD[(((size_t)slice * 4 + ks) * 64 + lane) * 8];
    f32x4 accsd[GJ];
#pragma unroll
    for (int g = 0; g < GJ; ++g) {
        accsd[g] = (f32x4){0.0f, 0.0f, 0.0f, 0.0f};
#pragma unroll
        for (int ks = 0; ks < 4; ++ks)
            accsd[g] = __builtin_amdgcn_mfma_f32_16x16x32_bf16(Sf[ks], Bf[g][ks], accsd[g], 0, 0, 0);
    }

    // Preload panels (b0, b0+1) -> LDS buffer 0 (1024 uint4)
    {
        const uint4* s4 = (const uint4*)(P + (size_t)b0 * PPAN);
        uint4 g0 = s4[tid], g1 = s4[tid + 256], g2 = s4[tid + 512], g3 = s4[tid + 768];
        uint4* d = (uint4*)sPan[0];
        d[tid] = g0; d[tid + 256] = g1; d[tid + 512] = g2; d[tid + 768] = g3;
    }
    __syncthreads();

    int cur = 0;
    for (int bp = 0; bp < BPB / 2; ++bp) {
        // Issue next 2-panel global loads (no wait — overlaps compute below)
        uint4 g0, g1, g2, g3;
        if (bp + 1 < BPB / 2) {
            const uint4* s4 = (const uint4*)(P + (size_t)(b0 + (bp + 1) * 2) * PPAN);
            g0 = s4[tid]; g1 = s4[tid + 256]; g2 = s4[tid + 512]; g3 = s4[tid + 768];
        }

#pragma unroll
        for (int sub = 0; sub < 2; ++sub) {
            const int bi = bp * 2 + sub;
            const int b = b0 + bi;
            const u16* sp = sPan[cur] + sub * PPAN;
            f32x4 acc[GJ][2];
#pragma unroll
            for (int g = 0; g < GJ; ++g)
#pragma unroll
                for (int t = 0; t < 2; ++t)
                    acc[g][t] = (f32x4){0.0f, 0.0f, 0.0f, 0.0f};
#pragma unroll
            for (int t = 0; t < 2; ++t) {
                short8 A0 = *(const short8*)&sp[(t * 4 + 0) * 512 + lane * 8];
                short8 A1 = *(const short8*)&sp[(t * 4 + 1) * 512 + lane * 8];
                short8 A2 = *(const short8*)&sp[(t * 4 + 2) * 512 + lane * 8];
                short8 A3 = *(const short8*)&sp[(t * 4 + 3) * 512 + lane * 8];
#pragma unroll
                for (int g = 0; g < GJ; ++g) {
                    acc[g][t] = __builtin_amdgcn_mfma_f32_16x16x32_bf16(A0, Bf[g][0], acc[g][t], 0, 0, 0);
                    acc[g][t] = __builtin_amdgcn_mfma_f32_16x16x32_bf16(A1, Bf[g][1], acc[g][t], 0, 0, 0);
                    acc[g][t] = __builtin_amdgcn_mfma_f32_16x16x32_bf16(A2, Bf[g][2], acc[g][t], 0, 0, 0);
                    acc[g][t] = __builtin_amdgcn_mfma_f32_16x16x32_bf16(A3, Bf[g][3], acc[g][t], 0, 0, 0);
                }
            }

            // Epilogue (max-free softmax). C/D: col=lane&15, row=quad*4+reg.
#pragma unroll
            for (int g = 0; g < GJ; ++g) {
                float den = 0.0f, num = 0.0f;
#pragma unroll
                for (int r = 0; r < 4; ++r) {
                    float p = __expf(acc[g][0][r]);
                    den += p;
                    num += p * acc[g][1][r];
                }
                den += __shfl_xor(den, 16); num += __shfl_xor(num, 16);
                den += __shfl_xor(den, 32); num += __shfl_xor(num, 32);
                // sd for (b, j=...+m) sits in lane (bi>>2)*16+m, reg bi&3.
                f32x4 s4v = accsd[g];
                int rr = bi & 3;
                float sdv = (rr == 0) ? s4v[0] : (rr == 1) ? s4v[1] : (rr == 2) ? s4v[2] : s4v[3];
                sdv = __shfl(sdv, ((bi >> 2) << 4) | m);
                if (quad == 0) {
                    int j = jb + wave * 64 + g * 16 + m;
                    if (j < NNODE) {
                        float z = sdv + num / den;
                        if (bf) ((u16*)out)[(size_t)b * NNODE + j] = f2bf(z);
                        else    ((float*)out)[(size_t)b * NNODE + j] = z;
                    }
                }
            }
        }

        // Commit prefetched panels to the other buffer (vmcnt wait lands
        // here, after both sub-iterations) then single barrier.
        if (bp + 1 < BPB / 2) {
            uint4* d = (uint4*)sPan[cur ^ 1];
            d[tid] = g0; d[tid + 256] = g1; d[tid + 512] = g2; d[tid + 768] = g3;
        }
        __syncthreads();
        cur ^= 1;
    }
}

extern "C" void kernel_launch(void* const* d_in, const int* in_sizes, int n_in,
                              void* d_out, int out_size, void* d_ws, size_t ws_size,
                              hipStream_t stream) {
    const int* x      = (const int*)d_in[0];
    const int* ei     = (const int*)d_in[1];
    const void* ew    = d_in[2];
    // d_in[3] batch: unused by reference
    const void* embed = d_in[4];
    const void* ggc   = d_in[5];
    const void* wih   = d_in[6];
    const void* whh   = d_in[7];
    const void* bih   = d_in[8];
    const void* bhh   = d_in[9];
    const void* W1w   = d_in[10];
    const void* W1b   = d_in[11];
    const void* W2w   = d_in[12];
    const void* W2b   = d_in[13];
    const void* Wtw   = d_in[14];
    const void* Wtb   = d_in[15];
    const void* qw    = d_in[16];
    const void* qb    = d_in[17];
    const void* W3w   = d_in[18];
    const void* W3b   = d_in[19];
    float* ws = (float*)d_ws;
    int* flag = (int*)d_ws;          // ws[0]

    // ws layout (floats):
    //   [0..64)              flag + pad
    //   [64..64+143232)      fp32 weight region W (see cvt_impl offsets)
    //   D = ws+143296, data region:
    //     agg0 = D+0       (102400)  zeroed k_cvt, scatter2-add, read k_gruatt
    //     h1   = D+102400  (102400)  k_gruatt -> k_att2
    //     Q2g  = D+204800  (102400)
    //     Q1g  = D+307200  (6400)
    //     P    = (u16*)(D+313600)  131072 fl  (written k_gruatt)
    //     SD   = (u16*)(D+444672)  8192 fl    (zeroed k_cvt, rows via k_att2)
    //     EB   = (u16*)(D+452864)  2080052 fl padded bf16 embed + guard row
    float* W = ws + 64;
    float* ew_f  = W + 0;
    float* ggc_f = W + 2048;
    float* wC    = W + 12048;
    float* bih_f = W + 92048;
    float* bhh_f = W + 92352;
    float* W1T   = W + 92656;
    float* W1b_f = W + 102656;
    float* W2T   = W + 102768;
    float* W2b_f = W + 112768;
    float* WtT   = W + 112880;
    float* Wtb_f = W + 122880;
    float* qw_f  = W + 122992;
    float* qb_f  = W + 123104;
    float* W3T   = W + 123120;
    float* W3b_f = W + 143120;

    float* D     = ws + 143296;
    float* agg0  = D;
    float* h1    = D + 102400;
    float* Q2g   = D + 204800;
    float* Q1g   = D + 307200;
    u16*   P     = (u16*)(D + 313600);
    u16*   SDp   = (u16*)(D + 444672);
    u16*   EB    = (u16*)(D + 452864);

    const size_t need_bytes = (size_t)(143296 + 452864) * 4 + (size_t)(NNODE + 1) * EBS * 2;
    const bool emode = (ws_size >= need_bytes);

    // Fused cvt+ecvt: blocks 0..481 = cvt (+agg0/SD zero), 482.. = ecvt.
    const int ecvt_blocks = ((NNODE + 1) * (EBS / 2) + 255) / 256;   // 8126
    k_cvt    <<<dim3(emode ? 482 + ecvt_blocks : 482), dim3(256), 0, stream>>>(
                                                   embed, flag, ew, ggc, wih, whh, bih, bhh,
                                                   W1w, W1b, W2w, W2b, Wtw, Wtb, qw, qb, W3w, W3b,
                                                   W, agg0, SDp, EB);
    k_scatter2<<<dim3(EE * (Hh / 2) / 256, 1), dim3(256), 0, stream>>>(flag, ei, ew_f, x, embed, agg0);
    k_gruatt <<<dim3(NN / GRB), dim3(512), 0, stream>>>(flag, x, embed, agg0, ggc_f, wC, bih_f, bhh_f,
                                                        W1T, W1b_f, W2T, W2b_f, WtT, Wtb_f,
                                                        h1, Q2g, Q1g, P);
    k_att2   <<<dim3(BB), dim3(256), 0, stream>>>(h1, Q1g, Q2g, qw_f, qb_f, W3T, W3b_f, SDp);
    if (emode)
        k_score<1><<<dim3(JBLK, BSPL), dim3(256), 0, stream>>>(flag, embed, EB, P, SDp, d_out);
    else
        k_score<0><<<dim3(JBLK, BSPL), dim3(256), 0, stream>>>(flag, embed, EB, P, SDp, d_out);
}

// Round 11
// 191.272 us; speedup vs baseline: 1.3987x; 1.0153x over previous
//
#include <hip/hip_runtime.h>
#include <hip/hip_bf16.h>

// Problem constants (from reference)
#define Hh    100
#define NN    1024     // B*L
#define BB    64
#define LL    16
#define EE    2048
#define NNODE 40000

#define BSPL  8        // b-loop split (slices)
#define BPB   (BB / BSPL)      // 8 b's per slice
#define PFR   8        // fragments per panel: f = t*4+ks, t in 0..1, ks in 0..3
#define PPAN  (PFR * 64 * 8)   // u16 per panel (4096)
#define GJ    4        // j-groups per wave (wave covers 64 embed rows)
#define EBS   104      // padded bf16 embed row stride (u16)
#define GRB   2        // rows per k_gruatt block

typedef unsigned short u16;
typedef __attribute__((ext_vector_type(8))) short short8;   // 8 bf16 = 4 VGPRs
typedef __attribute__((ext_vector_type(4))) float f32x4;    // MFMA C/D

__device__ __forceinline__ float bf2f(u16 u) {
    union { unsigned int i; float f; } v;
    v.i = ((unsigned int)u) << 16;
    return v.f;
}

__device__ __forceinline__ u16 f2bf(float f) {
    unsigned int x = __float_as_uint(f);
    unsigned int lsb = (x >> 16) & 1u;
    x += 0x7fffu + lsb;              // round-to-nearest-even
    return (u16)(x >> 16);
}

__device__ __forceinline__ float sigmoidf_(float x) {
    return 1.0f / (1.0f + expf(-x));
}

template <bool BF>
__device__ __forceinline__ float ldv(const void* p, size_t i) {
    if (BF) return bf2f(((const u16*)p)[i]);
    return ((const float*)p)[i];
}
__device__ __forceinline__ float ldvf(int flag, const void* p, size_t i) {
    return flag ? ldv<true>(p, i) : ldv<false>(p, i);
}

// ---------------------------------------------------------------------------
// k_cvt (fused with ecvt, UNCONDITIONAL — r9 measured: EB's 208-stride gives
// aligned 16B fragment loads, worth more than the conversion costs even for
// bf16 input). Per-BLOCK dtype self-detect (fp32 misdetect prob ~2^-128).
// Blocks 0..481: convert/transpose small tensors + zero agg0/SD.
// Blocks 482..: embed -> padded bf16 EB + zeroed guard row.
template <bool BF>
__device__ void cvt_impl(int t,
                         const void* ew, const void* ggc, const void* wih, const void* whh,
                         const void* bih, const void* bhh, const void* W1w, const void* W1b,
                         const void* W2w, const void* W2b, const void* Wtw, const void* Wtb,
                         const void* qw, const void* qb, const void* W3w, const void* W3b,
                         float* __restrict__ W) {
    const void* src; int si; int doff; int di;
    if      (t <   2048) { src = ew;  si = t;          doff = 0;      di = si; }
    else if (t <  12048) { src = ggc; si = t - 2048;   doff = 2048;   di = si; }                      // row-major
    else if (t <  42048) { src = wih; si = t - 12048;  doff = 12048;  { int r = si / 100, k = si - r * 100; di = k * 800 + (r % 100) * 8 + r / 100; } }
    else if (t <  72048) { src = whh; si = t - 42048;  doff = 12048;  { int r = si / 100, k = si - r * 100; di = k * 800 + (r % 100) * 8 + 3 + r / 100; } }
    else if (t <  72348) { src = bih; si = t - 72048;  doff = 92048;  di = si; }
    else if (t <  72648) { src = bhh; si = t - 72348;  doff = 92352;  di = si; }
    else if (t <  82648) { src = W1w; si = t - 72648;  doff = 92656;  di = (si % 100) * 100 + si / 100; }   // T
    else if (t <  82748) { src = W1b; si = t - 82648;  doff = 102656; di = si; }
    else if (t <  92748) { src = W2w; si = t - 82748;  doff = 102768; di = (si % 100) * 100 + si / 100; }   // T
    else if (t <  92848) { src = W2b; si = t - 92748;  doff = 112768; di = si; }
    else if (t < 102848) { src = Wtw; si = t - 92848;  doff = 112880; di = (si % 100) * 100 + si / 100; }   // T
    else if (t < 102948) { src = Wtb; si = t - 102848; doff = 122880; di = si; }
    else if (t < 103048) { src = qw;  si = t - 102948; doff = 122992; di = si; }
    else if (t < 103049) { src = qb;  si = t - 103048; doff = 123104; di = si; }
    else if (t < 123049) { src = W3w; si = t - 103049; doff = 123120; di = (si % 200) * 100 + si / 200; }   // T
    else                 { src = W3b; si = t - 123049; doff = 143120; di = si; }
    W[doff + di] = ldv<BF>(src, si);
}

__global__ void __launch_bounds__(256) k_cvt(const void* embed_raw, int* __restrict__ flag,
                      const void* ew, const void* ggc, const void* wih, const void* whh,
                      const void* bih, const void* bhh, const void* W1w, const void* W1b,
                      const void* W2w, const void* W2b, const void* Wtw, const void* Wtb,
                      const void* qw, const void* qb, const void* W3w, const void* W3b,
                      float* __restrict__ W, float* __restrict__ agg0,
                      u16* __restrict__ SD, u16* __restrict__ EB) {
    __shared__ int cnt;
    if (threadIdx.x == 0) cnt = 0;
    __syncthreads();
    const u16* eb16 = (const u16*)embed_raw;
    {
        float v = bf2f(eb16[threadIdx.x]);
        if (!(fabsf(v) <= 0.5f)) atomicAdd(&cnt, 1);   // counts NaN too
    }
    __syncthreads();
    const bool bf = (cnt == 0);
    const int bid = blockIdx.x;
    if (bid == 0 && threadIdx.x == 0) flag[0] = bf ? 1 : 0;
    if (bid < 482) {
        int t = bid * 256 + threadIdx.x;
        if (t < NN * Hh) agg0[t] = 0.0f;             // zero scatter target
        if (t < 8192) ((unsigned int*)SD)[t] = 0u;   // zero SD (16384 u16)
        if (t >= 123149) return;
        if (bf) cvt_impl<true >(t, ew, ggc, wih, whh, bih, bhh, W1w, W1b, W2w, W2b, Wtw, Wtb, qw, qb, W3w, W3b, W);
        else    cvt_impl<false>(t, ew, ggc, wih, whh, bih, bhh, W1w, W1b, W2w, W2b, Wtw, Wtb, qw, qb, W3w, W3b, W);
    } else {
        // ecvt: embed -> padded bf16 (stride EBS, cols 100..103 = 0) + guard row
        int t = (bid - 482) * 256 + threadIdx.x;
        const int total = (NNODE + 1) * (EBS / 2);
        if (t >= total) return;
        int r = t / (EBS / 2), c2 = t - r * (EBS / 2);
        int k0 = c2 * 2;
        unsigned int w = 0;
        if (r < NNODE && k0 + 1 < Hh) {
            if (bf) {
                w = *(const unsigned int*)&((const u16*)embed_raw)[(size_t)r * Hh + k0];
            } else {
                float2 e2 = *(const float2*)&((const float*)embed_raw)[(size_t)r * Hh + k0];
                w = (unsigned int)f2bf(e2.x) | ((unsigned int)f2bf(e2.y) << 16);
            }
        }
        ((unsigned int*)EB)[t] = w;
    }
}

// ---------------------------------------------------------------------------
// k_scatter2: agg0[dst] += ew[e] * h0[src]  (h0 = embed[x[src]], gathered
// directly — the GGC GEMM is applied AFTER aggregation in k_gruatt, valid by
// linearity). 2 cols per thread (u32/float2 loads).
__global__ void k_scatter2(const int* __restrict__ flag, const int* __restrict__ ei,
                           const float* __restrict__ ew, const int* __restrict__ x,
                           const void* __restrict__ embed, float* __restrict__ agg0) {
    int t = blockIdx.x * 256 + threadIdx.x;
    if (t >= EE * (Hh / 2)) return;
    int e = t / (Hh / 2), j2 = t - e * (Hh / 2);
    int j = j2 * 2;
    int src = ei[e], dst = ei[EE + e];
    const int fl = flag[0];
    float w = ew[e];
    float h0, h1v;
    size_t base = (size_t)x[src] * Hh + j;
    if (fl) {
        unsigned int u = *(const unsigned int*)&((const u16*)embed)[base];
        h0 = bf2f((u16)(u & 0xffff));
        h1v = bf2f((u16)(u >> 16));
    } else {
        float2 f2 = *(const float2*)&((const float*)embed)[base];
        h0 = f2.x; h1v = f2.y;
    }
    atomicAdd(&agg0[dst * Hh + j], w * h0);
    atomicAdd(&agg0[dst * Hh + j + 1], w * h1v);
}

// ---------------------------------------------------------------------------
// k_gruatt v2: 512 threads/block, k-loops split 2-way (kh = tid>>8), partials
// combined in LDS. (Round-5 measured fix for latency-bound regime.)
__global__ void __launch_bounds__(512) k_gruatt(const int* __restrict__ flag,
                      const int* __restrict__ x, const void* __restrict__ embed,
                      const float* __restrict__ agg0, const float* __restrict__ ggc_f,
                      const float* __restrict__ wC,
                      const float* __restrict__ bih, const float* __restrict__ bhh,
                      const float* __restrict__ W1T, const float* __restrict__ W1b,
                      const float* __restrict__ W2T, const float* __restrict__ W2b,
                      const float* __restrict__ WtT, const float* __restrict__ Wtb,
                      float* __restrict__ h1, float* __restrict__ Q2g,
                      float* __restrict__ Q1g, u16* __restrict__ P) {
    __shared__ float sG[GRB * Hh];    // agg0 rows
    __shared__ float sH0[GRB * Hh];   // embed rows
    __shared__ float sA[GRB * Hh];    // agg rows (post-GGC)
    __shared__ float sV[GRB * Hh];    // h1 rows
    __shared__ float sVT[GRB * Hh];   // VTs rows
    __shared__ float sPx[6 * 512];    // k-split partials (stride-1 per slot)
    const int tid = threadIdx.x;
    const int r0 = blockIdx.x * GRB;
    const int fl = flag[0];
    const int kh = tid >> 8;              // k-half
    const int o  = tid & 255;             // work item (i,j)
    const bool valid = (o < GRB * Hh);
    const int i = o / Hh, j = o - i * Hh; // meaningful when valid
    const int k0 = kh * 50, k1 = k0 + 50;

    // Load agg0 + gathered embed rows (contiguous per row; coalesced).
    if (tid < GRB * Hh) {
        sG[tid] = agg0[r0 * Hh + tid];
    } else if (tid < 2 * GRB * Hh) {
        int o2 = tid - GRB * Hh;
        int i2 = o2 / Hh, j2 = o2 - i2 * Hh;
        sH0[o2] = ldvf(fl, embed, (size_t)x[r0 + i2] * Hh + j2);
    }
    __syncthreads();

    // Phase 1: agg = agg0 @ ggc (k-split partial)
    {
        float acc = 0.0f;
        if (valid) {
            const float* gi = sG + i * Hh;
#pragma unroll 5
            for (int k = k0; k < k1; ++k) acc += gi[k] * ggc_f[k * Hh + j];
        }
        sPx[tid] = acc;
    }
    __syncthreads();
    if (valid && kh == 0) sA[o] = sPx[tid] + sPx[tid + 256];
    __syncthreads();

    // Phase 2: GRU gate sums (6 accumulators, k-split)
    {
        float p0 = 0, p1 = 0, p2 = 0, p3 = 0, p4 = 0, p5 = 0;
        if (valid) {
            const float* ai = sA + i * Hh;
            const float* hi = sH0 + i * Hh;
            const float* wbase = wC + j * 8;
#pragma unroll 5
            for (int k = k0; k < k1; ++k) {
                float a = ai[k], h = hi[k];
                const float* wr = wbase + k * 800;
                float4 w0 = *(const float4*)wr;
                float2 w1 = *(const float2*)(wr + 4);
                p0 += a * w0.x;
                p1 += a * w0.y;
                p2 += a * w0.z;
                p3 += h * w0.w;
                p4 += h * w1.x;
                p5 += h * w1.y;
            }
        }
        sPx[tid] = p0;             sPx[512 + tid] = p1;
        sPx[1024 + tid] = p2;      sPx[1536 + tid] = p3;
        sPx[2048 + tid] = p4;      sPx[2560 + tid] = p5;
    }
    __syncthreads();
    if (valid && kh == 0) {
        float s_ir = bih[j] + sPx[tid] + sPx[tid + 256];
        float s_iz = bih[j + Hh] + sPx[512 + tid] + sPx[512 + tid + 256];
        float s_in = bih[j + 2 * Hh] + sPx[1024 + tid] + sPx[1024 + tid + 256];
        float s_hr = bhh[j] + sPx[1536 + tid] + sPx[1536 + tid + 256];
        float s_hz = bhh[j + Hh] + sPx[2048 + tid] + sPx[2048 + tid + 256];
        float s_hn = bhh[j + 2 * Hh] + sPx[2560 + tid] + sPx[2560 + tid + 256];
        float r = sigmoidf_(s_ir + s_hr);
        float z = sigmoidf_(s_iz + s_hz);
        float n = tanhf(s_in + r * s_hn);
        float hv = (1.0f - z) * n + z * sH0[o];
        sV[o] = hv;
        h1[r0 * Hh + o] = hv;
    }
    __syncthreads();

    // Phase 3: Q2 = h1@W2T+b, VTs = h1@WtT+b (k-split)
    {
        float a2 = 0.0f, at = 0.0f;
        if (valid) {
            const float* vi = sV + i * Hh;
#pragma unroll 5
            for (int k = k0; k < k1; ++k) {
                float vk = vi[k];
                a2 += vk * W2T[k * Hh + j];
                at += vk * WtT[k * Hh + j];
            }
        }
        sPx[tid] = a2;
        sPx[512 + tid] = at;
    }
    __syncthreads();
    if (valid && kh == 0) {
        Q2g[r0 * Hh + o] = sPx[tid] + sPx[tid + 256] + W2b[j];
        sVT[o] = sPx[512 + tid] + sPx[512 + tid + 256] + Wtb[j];
    }
    __syncthreads();

    // Q1 for session-final row (global row r0+1 == 16b+15)
    if ((r0 & 15) == 14 && tid < Hh) {
        const float* vl = sV + Hh;
        float a1 = 0.0f;
#pragma unroll 4
        for (int k = 0; k < Hh; ++k) a1 += vl[k] * W1T[k * Hh + tid];
        Q1g[(r0 >> 4) * Hh + tid] = a1 + W1b[tid];
    }
    // P fragment writes for our GRB rows, both t-tiles (t0=VTs, t1=V).
    const int b = r0 >> 4;
    if (tid < GRB * 2 * 4 * 4) {
        int ii = tid >> 5, rest = tid & 31;
        int tt = rest >> 4, ks = (rest >> 2) & 3, qq = rest & 3;
        int mm = (r0 & 15) + ii;
        int col0 = ks * 32 + qq * 8;
        const float* srow = (tt == 0 ? sVT : sV) + ii * Hh;
        short8 t8;
#pragma unroll
        for (int e = 0; e < 8; ++e) {
            int col = col0 + e;
            t8[e] = (short)f2bf(col < Hh ? srow[col] : 0.0f);
        }
        *(short8*)&P[((size_t)b * PFR + tt * 4 + ks) * 512 + (qq * 16 + mm) * 8] = t8;
    }
}

// ---------------------------------------------------------------------------
// k_att2: light per-session tail — alpha (16x16-thread shfl-reduce), s_g,
// s_h, SD row write. One block per b. SD: slice b>>3, tile row b&7 (rows
// 8..15 pre-zeroed by k_cvt).
__global__ void __launch_bounds__(256) k_att2(const float* __restrict__ h1,
                    const float* __restrict__ Q1g, const float* __restrict__ Q2g,
                    const float* __restrict__ qw, const float* __restrict__ qb,
                    const float* __restrict__ W3T, const float* __restrict__ W3b,
                    u16* __restrict__ SD) {
    __shared__ float V[LL * Hh];
    __shared__ float AL[LL];
    __shared__ float SG[Hh];
    __shared__ float SH[Hh];
    const int b = blockIdx.x, tid = threadIdx.x;
    for (int o = tid; o < LL * Hh; o += 256) V[o] = h1[b * LL * Hh + o];
    __syncthreads();
    {
        int l = tid >> 4, t = tid & 15;
        float acc = 0.0f;
        for (int j = t; j < Hh; j += 16)
            acc += sigmoidf_(Q1g[b * Hh + j] + Q2g[(b * LL + l) * Hh + j]) * qw[j];
        acc += __shfl_xor(acc, 8);
        acc += __shfl_xor(acc, 4);
        acc += __shfl_xor(acc, 2);
        acc += __shfl_xor(acc, 1);
        if (t == 0) AL[l] = acc + qb[0];
    }
    __syncthreads();
    if (tid < Hh) {
        float acc = 0.0f;
#pragma unroll
        for (int l = 0; l < LL; ++l) acc += AL[l] * V[l * Hh + tid];
        SG[tid] = acc;
    }
    __syncthreads();
    if (tid < Hh) {
        float acc = W3b[tid];
#pragma unroll 4
        for (int k = 0; k < Hh; ++k) acc += V[(LL - 1) * Hh + k] * W3T[k * Hh + tid];
#pragma unroll 4
        for (int k = 0; k < Hh; ++k) acc += SG[k] * W3T[(Hh + k) * Hh + tid];
        SH[tid] = acc;
    }
    __syncthreads();
    // SD write: A-tile row (b&7) of slice (b>>3); 128 u16 scattered.
    if (tid < 128) {
        int ks = tid >> 5, qq = (tid >> 3) & 3, e = tid & 7;
        int col = ks * 32 + qq * 8 + e;
        float v = (col < Hh) ? SH[col] : 0.0f;
        SD[(((size_t)(b >> 3) * 4 + ks) * 64 + qq * 16 + (b & 7)) * 8 + e] = f2bf(v);
    }
}

// ---------------------------------------------------------------------------
// k_score v15: NO LDS, NO barriers. Key insight: each lane only ever reads
// its own 128 B of each P panel (fragment slice sp[f*512 + lane*8]), and
// those reads are perfectly coalesced in P's layout — so the global->LDS->
// barrier->read pipeline is pure overhead. Per-bi, fragments are loaded
// directly from P (L2-resident, 512 KB); waves are fully independent and
// the compiler pipelines loads across iterations with no barrier fences.
// EB fragment loads (aligned 16B), SD prologue, BSPL=8, GJ=4 unchanged.
__device__ __forceinline__ short8 load_efrag(const void* embed, bool bf, int j, int k0) {
    short8 v = {0, 0, 0, 0, 0, 0, 0, 0};
    if (j >= NNODE || k0 >= Hh) return v;
    if (bf) {
        const u16* row = (const u16*)embed + (size_t)j * Hh + k0;
        if (k0 + 8 <= Hh) {
            ushort4 a = *(const ushort4*)(row);
            ushort4 b = *(const ushort4*)(row + 4);
            v[0] = (short)a.x; v[1] = (short)a.y; v[2] = (short)a.z; v[3] = (short)a.w;
            v[4] = (short)b.x; v[5] = (short)b.y; v[6] = (short)b.z; v[7] = (short)b.w;
        } else {
            for (int e = 0; e < Hh - k0; ++e) v[e] = (short)row[e];
        }
    } else {
        const float* row = (const float*)embed + (size_t)j * Hh + k0;
        if (k0 + 8 <= Hh) {
            float4 a = *(const float4*)(row);
            float4 b = *(const float4*)(row + 4);
            v[0] = (short)f2bf(a.x); v[1] = (short)f2bf(a.y); v[2] = (short)f2bf(a.z); v[3] = (short)f2bf(a.w);
            v[4] = (short)f2bf(b.x); v[5] = (short)f2bf(b.y); v[6] = (short)f2bf(b.z); v[7] = (short)f2bf(b.w);
        } else {
            for (int e = 0; e < Hh - k0; ++e) v[e] = (short)f2bf(row[e]);
        }
    }
    return v;
}

#define JBLK  157   // ceil(40000/256)

template <int EMODE>
__global__ void __launch_bounds__(256) k_score(const int* __restrict__ flag,
                                               const void* __restrict__ embed,
                                               const u16* __restrict__ EB,
                                               const u16* __restrict__ P,
                                               const u16* __restrict__ SD,
                                               void* __restrict__ out) {
    const int jb = blockIdx.x * 256;
    const int slice = blockIdx.y;
    const int b0 = slice * BPB;
    const int tid = threadIdx.x;
    const bool bf = (flag[0] != 0);
    const int wave = tid >> 6, lane = tid & 63;
    const int m = lane & 15, quad = lane >> 4;

    // B fragments: 4 groups of 16 embed rows per wave, loaded once.
    short8 Bf[GJ][4];
#pragma unroll
    for (int g = 0; g < GJ; ++g)
#pragma unroll
        for (int ks = 0; ks < 4; ++ks) {
            int j = jb + wave * 64 + g * 16 + m;
            if (EMODE) {
                short8 v = {0, 0, 0, 0, 0, 0, 0, 0};
                if (j < NNODE)
                    v = *(const short8*)&EB[(size_t)j * EBS + ks * 32 + quad * 8];
                Bf[g][ks] = v;
            } else {
                Bf[g][ks] = load_efrag(embed, bf, j, ks * 32 + quad * 8);
            }
        }

    // SD prologue: sd[b0+r][j] for the 8 b's of this slice, 16 MFMAs.
    short8 Sf[4];
#pragma unroll
    for (int ks = 0; ks < 4; ++ks)
        Sf[ks] = *(const short8*)&SD[(((size_t)slice * 4 + ks) * 64 + lane) * 8];
    f32x4 accsd[GJ];
#pragma unroll
    for (int g = 0; g < GJ; ++g) {
        accsd[g] = (f32x4){0.0f, 0.0f, 0.0f, 0.0f};
#pragma unroll
        for (int ks = 0; ks < 4; ++ks)
            accsd[g] = __builtin_amdgcn_mfma_f32_16x16x32_bf16(Sf[ks], Bf[g][ks], accsd[g], 0, 0, 0);
    }

#pragma unroll
    for (int bi = 0; bi < BPB; ++bi) {
        const int b = b0 + bi;
        // Per-lane fragment base for this panel: lane's 16B slice of each
        // of the 8 fragments (coalesced: consecutive lanes -> consecutive 16B).
        const u16* pp = P + (size_t)b * PPAN + lane * 8;

        f32x4 acc[GJ][2];
#pragma unroll
        for (int g = 0; g < GJ; ++g)
#pragma unroll
            for (int t = 0; t < 2; ++t)
                acc[g][t] = (f32x4){0.0f, 0.0f, 0.0f, 0.0f};
#pragma unroll
        for (int t = 0; t < 2; ++t) {
            short8 A0 = *(const short8*)&pp[(t * 4 + 0) * 512];
            short8 A1 = *(const short8*)&pp[(t * 4 + 1) * 512];
            short8 A2 = *(const short8*)&pp[(t * 4 + 2) * 512];
            short8 A3 = *(const short8*)&pp[(t * 4 + 3) * 512];
#pragma unroll
            for (int g = 0; g < GJ; ++g) {
                acc[g][t] = __builtin_amdgcn_mfma_f32_16x16x32_bf16(A0, Bf[g][0], acc[g][t], 0, 0, 0);
                acc[g][t] = __builtin_amdgcn_mfma_f32_16x16x32_bf16(A1, Bf[g][1], acc[g][t], 0, 0, 0);
                acc[g][t] = __builtin_amdgcn_mfma_f32_16x16x32_bf16(A2, Bf[g][2], acc[g][t], 0, 0, 0);
                acc[g][t] = __builtin_amdgcn_mfma_f32_16x16x32_bf16(A3, Bf[g][3], acc[g][t], 0, 0, 0);
            }
        }

        // Epilogue (max-free softmax). C/D: col=lane&15, row=quad*4+reg.
#pragma unroll
        for (int g = 0; g < GJ; ++g) {
            float den = 0.0f, num = 0.0f;
#pragma unroll
            for (int r = 0; r < 4; ++r) {
                float p = __expf(acc[g][0][r]);
                den += p;
                num += p * acc[g][1][r];
            }
            den += __shfl_xor(den, 16); num += __shfl_xor(num, 16);
            den += __shfl_xor(den, 32); num += __shfl_xor(num, 32);
            // sd for (b, j=...+m) sits in lane (bi>>2)*16+m, reg bi&3.
            f32x4 s4v = accsd[g];
            int rr = bi & 3;
            float sdv = (rr == 0) ? s4v[0] : (rr == 1) ? s4v[1] : (rr == 2) ? s4v[2] : s4v[3];
            sdv = __shfl(sdv, ((bi >> 2) << 4) | m);
            if (quad == 0) {
                int j = jb + wave * 64 + g * 16 + m;
                if (j < NNODE) {
                    float z = sdv + num / den;
                    if (bf) ((u16*)out)[(size_t)b * NNODE + j] = f2bf(z);
                    else    ((float*)out)[(size_t)b * NNODE + j] = z;
                }
            }
        }
    }
}

extern "C" void kernel_launch(void* const* d_in, const int* in_sizes, int n_in,
                              void* d_out, int out_size, void* d_ws, size_t ws_size,
                              hipStream_t stream) {
    const int* x      = (const int*)d_in[0];
    const int* ei     = (const int*)d_in[1];
    const void* ew    = d_in[2];
    // d_in[3] batch: unused by reference
    const void* embed = d_in[4];
    const void* ggc   = d_in[5];
    const void* wih   = d_in[6];
    const void* whh   = d_in[7];
    const void* bih   = d_in[8];
    const void* bhh   = d_in[9];
    const void* W1w   = d_in[10];
    const void* W1b   = d_in[11];
    const void* W2w   = d_in[12];
    const void* W2b   = d_in[13];
    const void* Wtw   = d_in[14];
    const void* Wtb   = d_in[15];
    const void* qw    = d_in[16];
    const void* qb    = d_in[17];
    const void* W3w   = d_in[18];
    const void* W3b   = d_in[19];
    float* ws = (float*)d_ws;
    int* flag = (int*)d_ws;          // ws[0]

    // ws layout (floats):
    //   [0..64)              flag + pad
    //   [64..64+143232)      fp32 weight region W (see cvt_impl offsets)
    //   D = ws+143296, data region:
    //     agg0 = D+0       (102400)  zeroed k_cvt, scatter2-add, read k_gruatt
    //     h1   = D+102400  (102400)  k_gruatt -> k_att2
    //     Q2g  = D+204800  (102400)
    //     Q1g  = D+307200  (6400)
    //     P    = (u16*)(D+313600)  131072 fl  (written k_gruatt)
    //     SD   = (u16*)(D+444672)  8192 fl    (zeroed k_cvt, rows via k_att2)
    //     EB   = (u16*)(D+452864)  2080052 fl padded bf16 embed + guard row
    float* W = ws + 64;
    float* ew_f  = W + 0;
    float* ggc_f = W + 2048;
    float* wC    = W + 12048;
    float* bih_f = W + 92048;
    float* bhh_f = W + 92352;
    float* W1T   = W + 92656;
    float* W1b_f = W + 102656;
    float* W2T   = W + 102768;
    float* W2b_f = W + 112768;
    float* WtT   = W + 112880;
    float* Wtb_f = W + 122880;
    float* qw_f  = W + 122992;
    float* qb_f  = W + 123104;
    float* W3T   = W + 123120;
    float* W3b_f = W + 143120;

    float* D     = ws + 143296;
    float* agg0  = D;
    float* h1    = D + 102400;
    float* Q2g   = D + 204800;
    float* Q1g   = D + 307200;
    u16*   P     = (u16*)(D + 313600);
    u16*   SDp   = (u16*)(D + 444672);
    u16*   EB    = (u16*)(D + 452864);

    const size_t need_bytes = (size_t)(143296 + 452864) * 4 + (size_t)(NNODE + 1) * EBS * 2;
    const bool emode = (ws_size >= need_bytes);

    // Fused cvt+ecvt: blocks 0..481 = cvt (+agg0/SD zero), 482.. = ecvt.
    const int ecvt_blocks = ((NNODE + 1) * (EBS / 2) + 255) / 256;   // 8126
    k_cvt    <<<dim3(emode ? 482 + ecvt_blocks : 482), dim3(256), 0, stream>>>(
                                                   embed, flag, ew, ggc, wih, whh, bih, bhh,
                                                   W1w, W1b, W2w, W2b, Wtw, Wtb, qw, qb, W3w, W3b,
                                                   W, agg0, SDp, EB);
    k_scatter2<<<dim3(EE * (Hh / 2) / 256, 1), dim3(256), 0, stream>>>(flag, ei, ew_f, x, embed, agg0);
    k_gruatt <<<dim3(NN / GRB), dim3(512), 0, stream>>>(flag, x, embed, agg0, ggc_f, wC, bih_f, bhh_f,
                                                        W1T, W1b_f, W2T, W2b_f, WtT, Wtb_f,
                                                        h1, Q2g, Q1g, P);
    k_att2   <<<dim3(BB), dim3(256), 0, stream>>>(h1, Q1g, Q2g, qw_f, qb_f, W3T, W3b_f, SDp);
    if (emode)
        k_score<1><<<dim3(JBLK, BSPL), dim3(256), 0, stream>>>(flag, embed, EB, P, SDp, d_out);
    else
        k_score<0><<<dim3(JBLK, BSPL), dim3(256), 0, stream>>>(flag, embed, EB, P, SDp, d_out);
}